// Round 5
// baseline (1460.519 us; speedup 1.0000x reference)
//
#include <hip/hip_runtime.h>
#include <hip/hip_bf16.h>
#include <math.h>

#define S_LEN 4096
#define HID   2048
#define NH    8
#define NVH   16
#define DK    128
#define DV    128
#define KEY_DIM  (NH*DK)    // 1024
#define VAL_DIM  (NVH*DV)   // 2048
#define SCALE_Q  0.08838834764831845f  // 128^-0.5
#define CCH 64              // chunk length
#define NCH (S_LEN/CCH)     // 64 chunks

typedef __attribute__((ext_vector_type(8))) short short8;   // 8 bf16
typedef __attribute__((ext_vector_type(4))) float f32x4;

// ---------------------------------------------------------------------------
// float -> bf16 cast
// ---------------------------------------------------------------------------
__global__ __launch_bounds__(256) void cast_f2b(
    const float* __restrict__ in, __hip_bfloat16* __restrict__ out, int n) {
  int i = (blockIdx.x * 256 + threadIdx.x) * 4;
  if (i >= n) return;
  float4 v = *(const float4*)&in[i];
  union { __hip_bfloat16 b[4]; short4 s; } u;
  u.b[0] = __float2bfloat16(v.x); u.b[1] = __float2bfloat16(v.y);
  u.b[2] = __float2bfloat16(v.z); u.b[3] = __float2bfloat16(v.w);
  *(short4*)&out[i] = u.s;
}

// ---------------------------------------------------------------------------
// bf16 MFMA GEMM: C[M,N](fp32) = A[M,K] @ B[N,K]^T  (m97 structure)
// ---------------------------------------------------------------------------
__device__ __forceinline__ void lds_load16(const __hip_bfloat16* g,
                                           __hip_bfloat16* l) {
  __builtin_amdgcn_global_load_lds(
      (const __attribute__((address_space(1))) unsigned int*)g,
      (__attribute__((address_space(3))) unsigned int*)l, 16, 0, 0);
}

__global__ __launch_bounds__(256) void gemm_bf16_bt(
    const __hip_bfloat16* __restrict__ A, const __hip_bfloat16* __restrict__ B,
    float* __restrict__ C, int M, int N, int K) {
  __shared__ __hip_bfloat16 sA[128 * 32];
  __shared__ __hip_bfloat16 sB[128 * 32];
  const int t = threadIdx.x;
  const int wave = t >> 6, lane = t & 63;
  const int bm = blockIdx.y, bn = blockIdx.x;
  const int wm = (wave & 1) * 64, wn = (wave >> 1) * 64;

  f32x4 zero = {0.f, 0.f, 0.f, 0.f};
  f32x4 acc[4][4];
  #pragma unroll
  for (int i = 0; i < 4; i++)
    #pragma unroll
    for (int j = 0; j < 4; j++) acc[i][j] = zero;

  const int r0 = t >> 2,        c0 = (t & 3) * 8;
  const int r1 = (256 + t) >> 2, c1 = ((256 + t) & 3) * 8;
  const __hip_bfloat16* gA0 = A + (size_t)(bm * 128 + r0) * K + c0;
  const __hip_bfloat16* gA1 = A + (size_t)(bm * 128 + r1) * K + c1;
  const __hip_bfloat16* gB0 = B + (size_t)(bn * 128 + r0) * K + c0;
  const __hip_bfloat16* gB1 = B + (size_t)(bn * 128 + r1) * K + c1;
  __hip_bfloat16* lA0 = sA + (size_t)(wave * 64) * 8;
  __hip_bfloat16* lA1 = sA + (size_t)(256 + wave * 64) * 8;
  __hip_bfloat16* lB0 = sB + (size_t)(wave * 64) * 8;
  __hip_bfloat16* lB1 = sB + (size_t)(256 + wave * 64) * 8;

  const int fm = lane & 15, fk = (lane >> 4) * 8;

  for (int k0 = 0; k0 < K; k0 += 32) {
    lds_load16(gA0, lA0); lds_load16(gA1, lA1);
    lds_load16(gB0, lB0); lds_load16(gB1, lB1);
    gA0 += 32; gA1 += 32; gB0 += 32; gB1 += 32;
    __syncthreads();
    short8 a[4], b[4];
    #pragma unroll
    for (int i = 0; i < 4; i++)
      a[i] = *(const short8*)&sA[(size_t)(wm + i * 16 + fm) * 32 + fk];
    #pragma unroll
    for (int j = 0; j < 4; j++)
      b[j] = *(const short8*)&sB[(size_t)(wn + j * 16 + fm) * 32 + fk];
    #pragma unroll
    for (int i = 0; i < 4; i++)
      #pragma unroll
      for (int j = 0; j < 4; j++)
        acc[i][j] = __builtin_amdgcn_mfma_f32_16x16x32_bf16(a[i], b[j], acc[i][j], 0, 0, 0);
    __syncthreads();
  }
  #pragma unroll
  for (int i = 0; i < 4; i++) {
    #pragma unroll
    for (int j = 0; j < 4; j++) {
      int col = bn * 128 + wn + j * 16 + (lane & 15);
      int rw0 = bm * 128 + wm + i * 16 + (lane >> 4) * 4;
      #pragma unroll
      for (int r = 0; r < 4; r++)
        C[(size_t)(rw0 + r) * N + col] = acc[i][j][r];
    }
  }
}

// ---------------------------------------------------------------------------
// fp32 GEMM for the tiny N=16 projections (Wa, Wb)
// ---------------------------------------------------------------------------
__global__ __launch_bounds__(256) void gemm_bt(
    const float* __restrict__ A, const float* __restrict__ B,
    float* __restrict__ C, int M, int N, int K) {
  __shared__ float As[16][68];
  __shared__ float Bs[16][68];
  const int bm = blockIdx.y, bn = blockIdx.x;
  const int t = threadIdx.x;
  const int tx = t & 15, ty = t >> 4;
  const int lrow = t >> 2;
  const int lk0  = (t & 3) * 4;
  const int arow = bm * 64 + lrow;
  const int brow = bn * 64 + lrow;
  const bool bvalid = brow < N;

  float acc[4][4];
  #pragma unroll
  for (int i = 0; i < 4; i++)
    #pragma unroll
    for (int j = 0; j < 4; j++) acc[i][j] = 0.f;

  for (int k0 = 0; k0 < K; k0 += 16) {
    float4 av = *(const float4*)&A[(size_t)arow * K + k0 + lk0];
    float4 bv = bvalid ? *(const float4*)&B[(size_t)brow * K + k0 + lk0]
                       : make_float4(0.f, 0.f, 0.f, 0.f);
    As[lk0+0][lrow] = av.x; As[lk0+1][lrow] = av.y;
    As[lk0+2][lrow] = av.z; As[lk0+3][lrow] = av.w;
    Bs[lk0+0][lrow] = bv.x; Bs[lk0+1][lrow] = bv.y;
    Bs[lk0+2][lrow] = bv.z; Bs[lk0+3][lrow] = bv.w;
    __syncthreads();
    #pragma unroll
    for (int kk = 0; kk < 16; kk++) {
      float4 a = *(const float4*)&As[kk][ty * 4];
      float4 b = *(const float4*)&Bs[kk][tx * 4];
      float ar[4] = {a.x, a.y, a.z, a.w};
      float br[4] = {b.x, b.y, b.z, b.w};
      #pragma unroll
      for (int i = 0; i < 4; i++)
        #pragma unroll
        for (int j = 0; j < 4; j++) acc[i][j] += ar[i] * br[j];
    }
    __syncthreads();
  }
  #pragma unroll
  for (int i = 0; i < 4; i++) {
    int r = bm * 64 + ty * 4 + i;
    #pragma unroll
    for (int j = 0; j < 4; j++) {
      int c = bn * 64 + tx * 4 + j;
      if (c < N) C[(size_t)r * N + c] = acc[i][j];
    }
  }
}

// ---------------------------------------------------------------------------
// conv + SiLU + l2norm for q/k  -> bf16 output
// ---------------------------------------------------------------------------
__global__ __launch_bounds__(128) void conv_qk_kernel(
    const float* __restrict__ pre, const float* __restrict__ cw,
    __hip_bfloat16* __restrict__ out, float scale) {
  const int s = blockIdx.x, h = blockIdx.y, t = threadIdx.x;
  const int c = h * 128 + t;
  const float4 w = *(const float4*)&cw[c * 4];
  float y = pre[(size_t)s * KEY_DIM + c] * w.w;
  if (s >= 1) y += pre[(size_t)(s-1) * KEY_DIM + c] * w.z;
  if (s >= 2) y += pre[(size_t)(s-2) * KEY_DIM + c] * w.y;
  if (s >= 3) y += pre[(size_t)(s-3) * KEY_DIM + c] * w.x;
  float v = y / (1.f + expf(-y));
  float ss = v * v;
  #pragma unroll
  for (int off = 1; off < 64; off <<= 1) ss += __shfl_xor(ss, off, 64);
  __shared__ float red[2];
  if ((t & 63) == 0) red[t >> 6] = ss;
  __syncthreads();
  float inv = scale / sqrtf(red[0] + red[1] + 1e-6f);
  out[((size_t)s * NH + h) * 128 + t] = __float2bfloat16(v * inv);
}

// ---------------------------------------------------------------------------
// conv + SiLU for v
// ---------------------------------------------------------------------------
__global__ __launch_bounds__(256) void conv_v_kernel(
    const float* __restrict__ pre, const float* __restrict__ cw,
    float* __restrict__ out) {
  const int id = blockIdx.x * 256 + threadIdx.x;
  const int s = id >> 11, c = id & 2047;
  const float4 w = *(const float4*)&cw[c * 4];
  float y = pre[id] * w.w;
  if (s >= 1) y += pre[id - VAL_DIM]     * w.z;
  if (s >= 2) y += pre[id - 2*VAL_DIM]   * w.y;
  if (s >= 3) y += pre[id - 3*VAL_DIM]   * w.x;
  out[id] = y / (1.f + expf(-y));
}

// ---------------------------------------------------------------------------
// gl = -exp(A_log)*softplus(a+dt_bias)  (LOG decay), beta = sigmoid(b)
// ---------------------------------------------------------------------------
__global__ __launch_bounds__(256) void gb_kernel(
    const float* __restrict__ a_pre, const float* __restrict__ b_pre,
    const float* __restrict__ A_log, const float* __restrict__ dt_bias,
    float* __restrict__ gl, float* __restrict__ bv) {
  const int id = blockIdx.x * 256 + threadIdx.x;
  const int h = id & 15;
  float av = a_pre[id] + dt_bias[h];
  float sp = av > 20.f ? av : log1pf(expf(av));
  gl[id] = -expf(A_log[h]) * sp;
  bv[id] = 1.f / (1.f + expf(-b_pre[id]));
}

// ---------------------------------------------------------------------------
// Phase A v3 (unchanged)
// ---------------------------------------------------------------------------
__global__ __launch_bounds__(256) void phaseA_kernel(
    const __hip_bfloat16* __restrict__ kn, const float* __restrict__ vc,
    const float* __restrict__ gl, const float* __restrict__ bvv,
    __hip_bfloat16* __restrict__ Wb, __hip_bfloat16* __restrict__ UbT,
    float* __restrict__ Gbuf) {
  const int h = blockIdx.x, c = blockIdx.y, sh = h >> 1;
  const int t = threadIdx.x;
  __shared__ float kchT[128][68];   // [dk][j]
  __shared__ float vch[64][132];    // [j][n]
  __shared__ float mm[64][65];
  __shared__ float sol[64][257];    // odd stride: conflict-free per-column
  __shared__ float Gs[64], bet[64], lamB[64];

  {
    const int r = t >> 2, c0 = (t & 3) * 32;
    const __hip_bfloat16* krow = kn + (size_t)(c*64 + r)*KEY_DIM + sh*128 + c0;
    const float* vrow = vc + (size_t)(c*64 + r)*VAL_DIM + h*128 + c0;
    #pragma unroll
    for (int i = 0; i < 4; i++) {
      union { short8 s; __hip_bfloat16 b[8]; } kv;
      kv.s = *(const short8*)&krow[8*i];
      #pragma unroll
      for (int e = 0; e < 8; e++) kchT[c0+8*i+e][r] = __bfloat162float(kv.b[e]);
    }
    #pragma unroll
    for (int i = 0; i < 8; i++)
      *(float4*)&vch[r][c0 + 4*i] = *(const float4*)&vrow[4*i];
  }
  if (t < 64) {
    float g = gl[(size_t)(c*64 + t)*NVH + h];
    #pragma unroll
    for (int off = 1; off < 64; off <<= 1) {
      float p = __shfl_up(g, off, 64);
      if (t >= off) g += p;
    }
    Gs[t] = g;
    float b = bvv[(size_t)(c*64 + t)*NVH + h];
    bet[t] = b;
    lamB[t] = b * expf(g);
    Gbuf[((size_t)c*NVH + h)*64 + t] = g;
  }
  __syncthreads();

  {
    const int j0 = (t >> 4) * 4, l0 = (t & 15) * 4;
    float acc[4][4] = {};
    #pragma unroll 2
    for (int d = 0; d < 128; d++) {
      float4 kj = *(const float4*)&kchT[d][j0];
      float4 kl = *(const float4*)&kchT[d][l0];
      float aj[4] = {kj.x, kj.y, kj.z, kj.w};
      float al[4] = {kl.x, kl.y, kl.z, kl.w};
      #pragma unroll
      for (int i = 0; i < 4; i++)
        #pragma unroll
        for (int ii = 0; ii < 4; ii++)
          acc[i][ii] = fmaf(aj[i], al[ii], acc[i][ii]);
    }
    #pragma unroll
    for (int i = 0; i < 4; i++)
      #pragma unroll
      for (int ii = 0; ii < 4; ii++) {
        int j = j0 + i, l = l0 + ii;
        mm[j][l] = (l < j) ? bet[j] * expf(Gs[j] - Gs[l]) * acc[i][ii] : 0.f;
      }
  }
  __syncthreads();

  {
    const bool isW = t < 128;
    const int col = t & 127;
    for (int j = 0; j < 64; j++) {
      float s0 = isW ? lamB[j] * kchT[col][j] : bet[j] * vch[j][col];
      float s1 = 0.f;
      int l = 0;
      for (; l + 1 < j; l += 2) {
        s0 = fmaf(-mm[j][l],   sol[l][t],   s0);
        s1 = fmaf(-mm[j][l+1], sol[l+1][t], s1);
      }
      if (l < j) s0 = fmaf(-mm[j][l], sol[l][t], s0);
      sol[j][t] = s0 + s1;
    }
  }
  if (t < 128) {
    const size_t base = ((size_t)c*NVH + h) * 64 * 128;
    for (int j = 0; j < 64; j++)
      Wb[base + j*128 + t] = __float2bfloat16(sol[j][t]);
  } else {
    const int n = t - 128;
    const size_t ub = (((size_t)c*NVH + h) * 128 + n) * 64;
    for (int j0 = 0; j0 < 64; j0 += 4) {
      union { unsigned long long u; __hip_bfloat16 b[4]; } p;
      #pragma unroll
      for (int i = 0; i < 4; i++) p.b[i] = __float2bfloat16(sol[j0+i][t]);
      *(unsigned long long*)&UbT[ub + j0] = p.u;
    }
  }
}

// ---------------------------------------------------------------------------
// Phase B v8 = v7 (merged 1024-thread, 2 independent vt-streams per SIMD)
// + RACE FIX: v7 failed refcheck (absmax 0.168) because kT staging (waves
// 0-7, after mirror) raced with update-phase kT reads (all 16 waves, after
// barrier A) with no ordering between them. Fix: DOUBLE-BUFFER kT by chunk
// parity — update reads kT[c&1], stage writes kT[(c+1)&1]. No extra barrier.
// Re-audit of other LDS flows: dT(w pre-A/r post-A: ok via A), S16T(w post-A/
// r post-B: ok via B), Gs(w post-A by wave0 / r pre-A: ok via A). LDS ~90KB.
// ---------------------------------------------------------------------------
__device__ __forceinline__ void bar_lgkm() {
  asm volatile("s_waitcnt lgkmcnt(0)" ::: "memory");
  __builtin_amdgcn_s_barrier();
  asm volatile("" ::: "memory");
}

__global__ __launch_bounds__(1024, 4) void phaseB_kernel(
    const __hip_bfloat16* __restrict__ qn, const __hip_bfloat16* __restrict__ kn,
    const __hip_bfloat16* __restrict__ Wb, const __hip_bfloat16* __restrict__ UbT,
    const float* __restrict__ Gbuf,
    __hip_bfloat16* __restrict__ Db, float* __restrict__ obuf) {
  const int h = blockIdx.x, sh = h >> 1;
  const int t = threadIdx.x, lane = t & 63, w = t >> 6;   // w 0..15
  const int vt = w >> 3;          // value-dim half: waves 0-7 vt0, 8-15 vt1
  const int w2 = w & 7;
  const int fm = lane & 15, fq = lane >> 4;
  const int jt = w2 >> 1;         // j-tile (16 rows) for phase-1 / epilogue
  const int nh = w2 & 1;          // n-half within vt: tj in {2nh, 2nh+1}
  const int dt = w2 >> 1;         // dk-tile (32 rows) for update/mirror

  __shared__ __hip_bfloat16 S16T[2][64][136];  // S0 mirror per vt, [n_loc][dk]
  __shared__ __hip_bfloat16 kT[2][128][72];    // [buf][dk][j]  double-buffered
  __shared__ __hip_bfloat16 dT[2][64][72];     // e^{G_C-G_j} Delta per vt
  __shared__ float Gs[64];

  // k staging (threads 0..511): transpose, 4 dk x 4 j per thread
  const int kj = (t & 15) * 4, kd = ((t & 511) >> 4) * 4;
  const bool kstage = t < 512;
  const int j0 = 16*jt + fq*4;                 // epilogue rows

  f32x4 Sacc[2][2];
  #pragma unroll
  for (int ti = 0; ti < 2; ti++)
    #pragma unroll
    for (int i = 0; i < 2; i++) Sacc[ti][i] = (f32x4){0.f,0.f,0.f,0.f};
  for (int i = t; i < 2*64*136/2; i += 1024) ((unsigned int*)S16T)[i] = 0;

  ushort4 krg[4];
  short8 Qnext[4], Qcur[4];
  short8 Wnext[4], Wcur[4];
  unsigned long long Unext[2], Ucur[2];
  float gl64;

  auto prefetch = [&](int c) {
    const int cb = (c*NVH + h) * 64;
    const __hip_bfloat16* qbase = qn + (size_t)(c*64 + 16*jt + fm)*KEY_DIM + sh*128 + fq*8;
    #pragma unroll
    for (int k4 = 0; k4 < 4; k4++)
      Qnext[k4] = *(const short8*)&qbase[k4*32];
    if (kstage) {
      #pragma unroll
      for (int jj = 0; jj < 4; jj++)
        krg[jj] = *(const ushort4*)&kn[(size_t)(c*64 + kj + jj)*KEY_DIM + sh*128 + kd];
    }
    #pragma unroll
    for (int k4 = 0; k4 < 4; k4++)
      Wnext[k4] = *(const short8*)&Wb[(size_t)(cb + 16*jt + fm)*128 + k4*32 + fq*8];
    #pragma unroll
    for (int i = 0; i < 2; i++) {
      const int tj = 2*nh + i;
      Unext[i] = *(const unsigned long long*)
          &UbT[(((size_t)c*NVH + h)*128 + vt*64 + 16*tj + fm)*64 + j0];
    }
    if (t < 64) gl64 = Gbuf[(size_t)cb + t];
  };

  auto stage = [&](int buf) {
    if (t < 64) Gs[t] = gl64;
    if (kstage) {
      union { ushort4 v[4]; unsigned short u[16]; } kk;
      #pragma unroll
      for (int jj = 0; jj < 4; jj++) kk.v[jj] = krg[jj];
      #pragma unroll
      for (int dd = 0; dd < 4; dd++) {
        union { unsigned short u[4]; unsigned long long q; } p;
        #pragma unroll
        for (int jj = 0; jj < 4; jj++) p.u[jj] = kk.u[jj*4 + dd];
        *(unsigned long long*)&kT[buf][kd + dd][kj] = p.q;
      }
    }
  };

  prefetch(0);
  #pragma unroll
  for (int k4 = 0; k4 < 4; k4++) { Qcur[k4] = Qnext[k4]; Wcur[k4] = Wnext[k4]; }
  #pragma unroll
  for (int i = 0; i < 2; i++) Ucur[i] = Unext[i];
  bar_lgkm();               // S16T zero-init visible
  stage(0);
  bar_lgkm();               // chunk-0 staging + Gs visible

  for (int c = 0; c < NCH; c++) {
    // issue prefetch for c+1 (independent; drains at the reg-copy at chunk end)
    prefetch(c + 1 < NCH ? c + 1 : 0);

    // (1)+(2): X = W S0, opart_raw = q S0   (wave: vt x j-tile jt x n-half nh)
    f32x4 aX[2], aO[2];
    #pragma unroll
    for (int i = 0; i < 2; i++) {
      aX[i] = (f32x4){0.f,0.f,0.f,0.f};
      aO[i] = (f32x4){0.f,0.f,0.f,0.f};
    }
    __builtin_amdgcn_s_setprio(1);
    #pragma unroll
    for (int k4 = 0; k4 < 4; k4++) {
      #pragma unroll
      for (int i = 0; i < 2; i++) {
        const int tj = 2*nh + i;
        short8 b = *(const short8*)&S16T[vt][16*tj + fm][k4*32 + fq*8];
        aX[i] = __builtin_amdgcn_mfma_f32_16x16x32_bf16(Wcur[k4], b, aX[i], 0, 0, 0);
        aO[i] = __builtin_amdgcn_mfma_f32_16x16x32_bf16(Qcur[k4], b, aO[i], 0, 0, 0);
      }
    }
    __builtin_amdgcn_s_setprio(0);
    // epilogue: Delta, dT, stores. o_intra[j] = e^{G_j} (q_j . S0) -> scale aO.
    const int cb = (c*NVH + h) * 64;
    const float gC = Gs[63];
    float er[4], os[4];
    #pragma unroll
    for (int r2 = 0; r2 < 4; r2++) {
      const float gj = Gs[j0 + r2];
      os[r2] = expf(gj);
      er[r2] = expf(gC - gj);
    }
    #pragma unroll
    for (int i = 0; i < 2; i++) {
      const int tj = 2*nh + i;
      const int n = 16*tj + fm;
      union { unsigned long long u; __hip_bfloat16 b[4]; } u4;
      u4.u = Ucur[i];
      union { __hip_bfloat16 b[4]; unsigned long long u; } pd;
      #pragma unroll
      for (int r2 = 0; r2 < 4; r2++) {
        const int j = j0 + r2;
        float d = __bfloat162float(u4.b[r2]) - aX[i][r2];
        Db[(size_t)(cb + j)*128 + vt*64 + n] = __float2bfloat16(d);
        pd.b[r2] = __float2bfloat16(d * er[r2]);
        obuf[((size_t)(c*64 + j)*NVH + h)*128 + vt*64 + n] = aO[i][r2] * os[r2];
      }
      *(unsigned long long*)&dT[vt][n][j0] = pd.u;
    }
    // decay S
    const float lamC = expf(gC);
    #pragma unroll
    for (int ti = 0; ti < 2; ti++)
      #pragma unroll
      for (int i = 0; i < 2; i++)
        #pragma unroll
        for (int r2 = 0; r2 < 4; r2++) Sacc[ti][i][r2] *= lamC;
    // barrier A: dT visible; all phase-1 S16T reads + epilogue Gs reads done.
    bar_lgkm();
    // (3): S += K^T dT'   (wave: vt x dk-tile dt x n-half nh; kT[c&1])
    __builtin_amdgcn_s_setprio(1);
    #pragma unroll
    for (int ti = 0; ti < 2; ti++) {
      const int m0 = 32*dt + 16*ti;
      #pragma unroll
      for (int kk0 = 0; kk0 < 64; kk0 += 32) {
        short8 aK = *(const short8*)&kT[c & 1][m0 + fm][kk0 + fq*8];
        #pragma unroll
        for (int i = 0; i < 2; i++) {
          const int tj = 2*nh + i;
          short8 bD = *(const short8*)&dT[vt][16*tj + fm][kk0 + fq*8];
          Sacc[ti][i] = __builtin_amdgcn_mfma_f32_16x16x32_bf16(aK, bD, Sacc[ti][i], 0, 0, 0);
        }
      }
    }
    __builtin_amdgcn_s_setprio(0);
    // refresh bf16 mirror (cols 32dt..32dt+32, rows n in this wave's n-half)
    #pragma unroll
    for (int ti = 0; ti < 2; ti++) {
      const int dk0 = 32*dt + 16*ti + fq*4;
      #pragma unroll
      for (int i = 0; i < 2; i++) {
        const int tj = 2*nh + i;
        const int n = 16*tj + fm;
        union { __hip_bfloat16 b[4]; unsigned long long u; } ps;
        #pragma unroll
        for (int r2 = 0; r2 < 4; r2++) ps.b[r2] = __float2bfloat16(Sacc[ti][i][r2]);
        *(unsigned long long*)&S16T[vt][n][dk0] = ps.u;
      }
    }
    // stage c+1 k -> kT[(c+1)&1] (other buffer than update reads); regs -> cur
    stage((c + 1) & 1);
    #pragma unroll
    for (int k4 = 0; k4 < 4; k4++) { Qcur[k4] = Qnext[k4]; Wcur[k4] = Wnext[k4]; }
    #pragma unroll
    for (int i = 0; i < 2; i++) Ucur[i] = Unext[i];
    // barrier B: S16T mirror + Gs + kT staging visible for chunk c+1
    bar_lgkm();
  }
}

// ---------------------------------------------------------------------------
// Phase C v2 (unchanged)
// ---------------------------------------------------------------------------
__global__ __launch_bounds__(256) void phaseC_kernel(
    const __hip_bfloat16* __restrict__ qn, const __hip_bfloat16* __restrict__ kn,
    const float* __restrict__ Gbuf, const __hip_bfloat16* __restrict__ Db,
    float* __restrict__ obuf) {
  const int h = blockIdx.x, c = blockIdx.y, sh = h >> 1;
  const int t = threadIdx.x;
  __shared__ float qch[64][132];
  __shared__ float kch[64][132];
  __shared__ float PT[64][68];              // [l][j]
  __shared__ __hip_bfloat16 dch[64][136];   // [l][n]
  __shared__ float Gs[64];

  {
    const int r = t >> 2, c0 = (t & 3) * 32;
    const __hip_bfloat16* qrow = qn + (size_t)(c*64 + r)*KEY_DIM + sh*128 + c0;
    const __hip_bfloat16* krow = kn + (size_t)(c*64 + r)*KEY_DIM + sh*128 + c0;
    #pragma unroll
    for (int i = 0; i < 4; i++) {
      union { short8 s; __hip_bfloat16 b[8]; } qv, kv;
      qv.s = *(const short8*)&qrow[8*i];
      kv.s = *(const short8*)&krow[8*i];
      #pragma unroll
      for (int e = 0; e < 8; e++) {
        qch[r][c0 + 8*i + e] = __bfloat162float(qv.b[e]);
        kch[r][c0 + 8*i + e] = __bfloat162float(kv.b[e]);
      }
    }
    const __hip_bfloat16* drow = Db + ((size_t)c*NVH + h)*64*128 + (size_t)r*128 + c0;
    #pragma unroll
    for (int i = 0; i < 4; i++)
      *(short8*)&dch[r][c0 + 8*i] = *(const short8*)&drow[8*i];
  }
  if (t < 64) Gs[t] = Gbuf[((size_t)c*NVH + h)*64 + t];
  __syncthreads();

  {
    const int jb = t >> 4, lb = t & 15;
    const int j0 = jb * 4, l0 = lb * 4;
    float acc[4][4] = {};
    for (int dd = 0; dd < 32; dd++) {
      const int d4 = ((dd + lb) & 31) * 4;
      float4 qj[4], kl[4];
      #pragma unroll
      for (int i = 0; i < 4; i++) {
        qj[i] = *(const float4*)&qch[j0 + i][d4];
        kl[i] = *(const float4*)&kch[l0 + i][d4];
      }
      #pragma unroll
      for (int i = 0; i < 4; i++)
        #pragma unroll
        for (int ii = 0; ii < 4; ii++)
          acc[i][ii] += qj[i].x*kl[ii].x + qj[i].y*kl[ii].y
                      + qj[i].z*kl[ii].z + qj[i].w*kl[ii].w;
    }
    #pragma unroll
    for (int i = 0; i < 4; i++)
      #pragma unroll
      for (int ii = 0; ii < 4; ii++) {
        int j = j0 + i, l = l0 + ii;
        PT[l][j] = (l <= j) ? expf(Gs[j] - Gs[l]) * acc[i][ii] : 0.f;
      }
  }
  __syncthreads();

  {
    const int j0 = (t >> 5) * 8;
    const int n0 = (t & 31) * 4;
    float acc2[8][4] = {};
    for (int l = 0; l < 64; l++) {
      float4 p0 = *(const float4*)&PT[l][j0];
      float4 p1 = *(const float4*)&PT[l][j0 + 4];
      float pj[8] = {p0.x,p0.y,p0.z,p0.w,p1.x,p1.y,p1.z,p1.w};
      float dv[4];
      #pragma unroll
      for (int ii = 0; ii < 4; ii++) dv[ii] = __bfloat162float(dch[l][n0 + ii]);
      #pragma unroll
      for (int i = 0; i < 8; i++)
        #pragma unroll
        for (int ii = 0; ii < 4; ii++)
          acc2[i][ii] += pj[i] * dv[ii];
    }
    #pragma unroll
    for (int i = 0; i < 8; i++) {
      float* orow = obuf + ((size_t)(c*64 + j0 + i)*NVH + h)*128 + n0;
      float4 o4 = *(const float4*)orow;
      o4.x += acc2[i][0]; o4.y += acc2[i][1];
      o4.z += acc2[i][2]; o4.w += acc2[i][3];
      *(float4*)orow = o4;
    }
  }
}

// ---------------------------------------------------------------------------
// Gated RMSNorm -> bf16
// ---------------------------------------------------------------------------
__global__ __launch_bounds__(128) void norm_kernel(
    const float* __restrict__ o, const float* __restrict__ gate,
    const float* __restrict__ w_norm, __hip_bfloat16* __restrict__ og) {
  const int s = blockIdx.x, h = blockIdx.y, t = threadIdx.x;
  const size_t idx = (size_t)s * VAL_DIM + h * 128 + t;
  float gt = gate[idx];
  float val = o[idx] * (gt / (1.f + expf(-gt)));
  float ss = val * val;
  #pragma unroll
  for (int off = 1; off < 64; off <<= 1) ss += __shfl_xor(ss, off, 64);
  __shared__ float red[2];
  if ((t & 63) == 0) red[t >> 6] = ss;
  __syncthreads();
  float ms = (red[0] + red[1]) * (1.f / 128.f);
  og[idx] = __float2bfloat16(val * (1.f / sqrtf(ms + 1e-6f)) * w_norm[t]);
}

// ---------------------------------------------------------------------------
extern "C" void kernel_launch(void* const* d_in, const int* in_sizes, int n_in,
                              void* d_out, int out_size, void* d_ws, size_t ws_size,
                              hipStream_t stream) {
  const float* x       = (const float*)d_in[0];
  const float* Wq      = (const float*)d_in[1];
  const float* Wk      = (const float*)d_in[2];
  const float* Wv      = (const float*)d_in[3];
  const float* Wa      = (const float*)d_in[4];
  const float* Wb_     = (const float*)d_in[5];
  const float* Wg      = (const float*)d_in[6];
  const float* Wo      = (const float*)d_in[7];
  const float* conv_q  = (const float*)d_in[8];
  const float* conv_k  = (const float*)d_in[9];
  const float* conv_v  = (const float*)d_in[10];
  const float* A_log   = (const float*)d_in[11];
  const float* dt_bias = (const float*)d_in[12];
  const float* w_norm  = (const float*)d_in[13];
  float* out = (float*)d_out;

  const size_t QK = (size_t)S_LEN * KEY_DIM;   // 4.19M
  const size_t SV = (size_t)S_LEN * VAL_DIM;   // 8.39M
  const size_t SM = (size_t)S_LEN * NVH;       // 65536

  float* W = (float*)d_ws;
  float* q_pre = W;
  float* k_pre = q_pre + QK;
  float* v_pre = k_pre + QK;       // SV floats; later: UbT (bf16) | Db (bf16)
  float* qn    = v_pre + SV;       // bf16 now (slot kept float-sized)
  float* kn    = qn + QK;          // bf16 now; later: ogb
  float* vcb   = kn + QK;          // SV floats; later: obuf
  float* a_pre = vcb + SV;
  float* b_pre = a_pre + SM;
  float* glb   = b_pre + SM;
  float* beta  = glb + SM;
  float* Gbuf  = beta + SM;        // NCH*NVH*64 = 65536
  __hip_bfloat16* xb = (__hip_bfloat16*)(Gbuf + SM);  // 8.39M bf16; later: Wb
  __hip_bfloat16* wb = xb + SV;                       // up to 4.19M bf16

  float* gate = q_pre;             // after convs
  float* obuf = vcb;               // after phase A
  __hip_bfloat16* qnb = (__hip_bfloat16*)qn;
  __hip_bfloat16* knb = (__hip_bfloat16*)kn;
  __hip_bfloat16* ogb = (__hip_bfloat16*)kn;  // norm output (after phaseC)
  __hip_bfloat16* Wbb = xb;                   // after gate gemm
  __hip_bfloat16* UbT = (__hip_bfloat16*)v_pre;
  __hip_bfloat16* Db  = (__hip_bfloat16*)(v_pre + SV/2);

  const int NC = 256 * 4;
  cast_f2b<<<(S_LEN*HID)/NC, 256, 0, stream>>>(x, xb, S_LEN*HID);

  cast_f2b<<<(KEY_DIM*HID)/NC, 256, 0, stream>>>(Wq, wb, KEY_DIM*HID);
  gemm_bf16_bt<<<dim3(KEY_DIM/128, S_LEN/128), 256, 0, stream>>>(xb, wb, q_pre, S_LEN, KEY_DIM, HID);
  cast_f2b<<<(KEY_DIM*HID)/NC, 256, 0, stream>>>(Wk, wb, KEY_DIM*HID);
  gemm_bf16_bt<<<dim3(KEY_DIM/128, S_LEN/128), 256, 0, stream>>>(xb, wb, k_pre, S_LEN, KEY_DIM, HID);
  cast_f2b<<<(VAL_DIM*HID)/NC, 256, 0, stream>>>(Wv, wb, VAL_DIM*HID);
  gemm_bf16_bt<<<dim3(VAL_DIM/128, S_LEN/128), 256, 0, stream>>>(xb, wb, v_pre, S_LEN, VAL_DIM, HID);
  gemm_bt<<<dim3(1, S_LEN/64), 256, 0, stream>>>(x, Wa, a_pre, S_LEN, NVH, HID);
  gemm_bt<<<dim3(1, S_LEN/64), 256, 0, stream>>>(x, Wb_, b_pre, S_LEN, NVH, HID);

  conv_qk_kernel<<<dim3(S_LEN, NH), 128, 0, stream>>>(q_pre, conv_q, qnb, SCALE_Q);
  conv_qk_kernel<<<dim3(S_LEN, NH), 128, 0, stream>>>(k_pre, conv_k, knb, 1.f);
  conv_v_kernel<<<(S_LEN*VAL_DIM)/256, 256, 0, stream>>>(v_pre, conv_v, vcb);
  gb_kernel<<<(S_LEN*NVH)/256, 256, 0, stream>>>(a_pre, b_pre, A_log, dt_bias, glb, beta);

  cast_f2b<<<(VAL_DIM*HID)/NC, 256, 0, stream>>>(Wg, wb, VAL_DIM*HID);
  gemm_bf16_bt<<<dim3(VAL_DIM/128, S_LEN/128), 256, 0, stream>>>(xb, wb, gate, S_LEN, VAL_DIM, HID);

  // chunked delta-rule scan
  phaseA_kernel<<<dim3(NVH, NCH), 256, 0, stream>>>(knb, vcb, glb, beta, Wbb, UbT, Gbuf);
  phaseB_kernel<<<NVH, 1024, 0, stream>>>(qnb, knb, Wbb, UbT, Gbuf, Db, obuf);
  phaseC_kernel<<<dim3(NVH, NCH), 256, 0, stream>>>(qnb, knb, Gbuf, Db, obuf);

  norm_kernel<<<dim3(S_LEN, NVH), 128, 0, stream>>>(obuf, gate, w_norm, ogb);

  cast_f2b<<<(HID*VAL_DIM)/NC, 256, 0, stream>>>(Wo, wb, HID*VAL_DIM);
  gemm_bf16_bt<<<dim3(HID/128, S_LEN/128), 256, 0, stream>>>(ogb, wb, out, S_LEN, HID, VAL_DIM);
}

// Round 6
// 1200.932 us; speedup vs baseline: 1.2162x; 1.2162x over previous
//
#include <hip/hip_runtime.h>
#include <hip/hip_bf16.h>
#include <math.h>

#define S_LEN 4096
#define HID   2048
#define NH    8
#define NVH   16
#define DK    128
#define DV    128
#define KEY_DIM  (NH*DK)    // 1024
#define VAL_DIM  (NVH*DV)   // 2048
#define SCALE_Q  0.08838834764831845f  // 128^-0.5
#define CCH 64              // chunk length
#define NCH (S_LEN/CCH)     // 64 chunks

typedef __attribute__((ext_vector_type(8))) short short8;   // 8 bf16
typedef __attribute__((ext_vector_type(4))) float f32x4;

// ---------------------------------------------------------------------------
// float -> bf16 cast
// ---------------------------------------------------------------------------
__global__ __launch_bounds__(256) void cast_f2b(
    const float* __restrict__ in, __hip_bfloat16* __restrict__ out, int n) {
  int i = (blockIdx.x * 256 + threadIdx.x) * 4;
  if (i >= n) return;
  float4 v = *(const float4*)&in[i];
  union { __hip_bfloat16 b[4]; short4 s; } u;
  u.b[0] = __float2bfloat16(v.x); u.b[1] = __float2bfloat16(v.y);
  u.b[2] = __float2bfloat16(v.z); u.b[3] = __float2bfloat16(v.w);
  *(short4*)&out[i] = u.s;
}

// ---------------------------------------------------------------------------
// bf16 MFMA GEMM: C[M,N](fp32) = A[M,K] @ B[N,K]^T  (m97 structure)
// ---------------------------------------------------------------------------
__device__ __forceinline__ void lds_load16(const __hip_bfloat16* g,
                                           __hip_bfloat16* l) {
  __builtin_amdgcn_global_load_lds(
      (const __attribute__((address_space(1))) unsigned int*)g,
      (__attribute__((address_space(3))) unsigned int*)l, 16, 0, 0);
}

__global__ __launch_bounds__(256) void gemm_bf16_bt(
    const __hip_bfloat16* __restrict__ A, const __hip_bfloat16* __restrict__ B,
    float* __restrict__ C, int M, int N, int K) {
  __shared__ __hip_bfloat16 sA[128 * 32];
  __shared__ __hip_bfloat16 sB[128 * 32];
  const int t = threadIdx.x;
  const int wave = t >> 6, lane = t & 63;
  const int bm = blockIdx.y, bn = blockIdx.x;
  const int wm = (wave & 1) * 64, wn = (wave >> 1) * 64;

  f32x4 zero = {0.f, 0.f, 0.f, 0.f};
  f32x4 acc[4][4];
  #pragma unroll
  for (int i = 0; i < 4; i++)
    #pragma unroll
    for (int j = 0; j < 4; j++) acc[i][j] = zero;

  const int r0 = t >> 2,        c0 = (t & 3) * 8;
  const int r1 = (256 + t) >> 2, c1 = ((256 + t) & 3) * 8;
  const __hip_bfloat16* gA0 = A + (size_t)(bm * 128 + r0) * K + c0;
  const __hip_bfloat16* gA1 = A + (size_t)(bm * 128 + r1) * K + c1;
  const __hip_bfloat16* gB0 = B + (size_t)(bn * 128 + r0) * K + c0;
  const __hip_bfloat16* gB1 = B + (size_t)(bn * 128 + r1) * K + c1;
  __hip_bfloat16* lA0 = sA + (size_t)(wave * 64) * 8;
  __hip_bfloat16* lA1 = sA + (size_t)(256 + wave * 64) * 8;
  __hip_bfloat16* lB0 = sB + (size_t)(wave * 64) * 8;
  __hip_bfloat16* lB1 = sB + (size_t)(256 + wave * 64) * 8;

  const int fm = lane & 15, fk = (lane >> 4) * 8;

  for (int k0 = 0; k0 < K; k0 += 32) {
    lds_load16(gA0, lA0); lds_load16(gA1, lA1);
    lds_load16(gB0, lB0); lds_load16(gB1, lB1);
    gA0 += 32; gA1 += 32; gB0 += 32; gB1 += 32;
    __syncthreads();
    short8 a[4], b[4];
    #pragma unroll
    for (int i = 0; i < 4; i++)
      a[i] = *(const short8*)&sA[(size_t)(wm + i * 16 + fm) * 32 + fk];
    #pragma unroll
    for (int j = 0; j < 4; j++)
      b[j] = *(const short8*)&sB[(size_t)(wn + j * 16 + fm) * 32 + fk];
    #pragma unroll
    for (int i = 0; i < 4; i++)
      #pragma unroll
      for (int j = 0; j < 4; j++)
        acc[i][j] = __builtin_amdgcn_mfma_f32_16x16x32_bf16(a[i], b[j], acc[i][j], 0, 0, 0);
    __syncthreads();
  }
  #pragma unroll
  for (int i = 0; i < 4; i++) {
    #pragma unroll
    for (int j = 0; j < 4; j++) {
      int col = bn * 128 + wn + j * 16 + (lane & 15);
      int rw0 = bm * 128 + wm + i * 16 + (lane >> 4) * 4;
      #pragma unroll
      for (int r = 0; r < 4; r++)
        C[(size_t)(rw0 + r) * N + col] = acc[i][j][r];
    }
  }
}

// ---------------------------------------------------------------------------
// fp32 GEMM for the tiny N=16 projections (Wa, Wb)
// ---------------------------------------------------------------------------
__global__ __launch_bounds__(256) void gemm_bt(
    const float* __restrict__ A, const float* __restrict__ B,
    float* __restrict__ C, int M, int N, int K) {
  __shared__ float As[16][68];
  __shared__ float Bs[16][68];
  const int bm = blockIdx.y, bn = blockIdx.x;
  const int t = threadIdx.x;
  const int tx = t & 15, ty = t >> 4;
  const int lrow = t >> 2;
  const int lk0  = (t & 3) * 4;
  const int arow = bm * 64 + lrow;
  const int brow = bn * 64 + lrow;
  const bool bvalid = brow < N;

  float acc[4][4];
  #pragma unroll
  for (int i = 0; i < 4; i++)
    #pragma unroll
    for (int j = 0; j < 4; j++) acc[i][j] = 0.f;

  for (int k0 = 0; k0 < K; k0 += 16) {
    float4 av = *(const float4*)&A[(size_t)arow * K + k0 + lk0];
    float4 bv = bvalid ? *(const float4*)&B[(size_t)brow * K + k0 + lk0]
                       : make_float4(0.f, 0.f, 0.f, 0.f);
    As[lk0+0][lrow] = av.x; As[lk0+1][lrow] = av.y;
    As[lk0+2][lrow] = av.z; As[lk0+3][lrow] = av.w;
    Bs[lk0+0][lrow] = bv.x; Bs[lk0+1][lrow] = bv.y;
    Bs[lk0+2][lrow] = bv.z; Bs[lk0+3][lrow] = bv.w;
    __syncthreads();
    #pragma unroll
    for (int kk = 0; kk < 16; kk++) {
      float4 a = *(const float4*)&As[kk][ty * 4];
      float4 b = *(const float4*)&Bs[kk][tx * 4];
      float ar[4] = {a.x, a.y, a.z, a.w};
      float br[4] = {b.x, b.y, b.z, b.w};
      #pragma unroll
      for (int i = 0; i < 4; i++)
        #pragma unroll
        for (int j = 0; j < 4; j++) acc[i][j] += ar[i] * br[j];
    }
    __syncthreads();
  }
  #pragma unroll
  for (int i = 0; i < 4; i++) {
    int r = bm * 64 + ty * 4 + i;
    #pragma unroll
    for (int j = 0; j < 4; j++) {
      int c = bn * 64 + tx * 4 + j;
      if (c < N) C[(size_t)r * N + c] = acc[i][j];
    }
  }
}

// ---------------------------------------------------------------------------
// conv + SiLU + l2norm for q/k  -> bf16 output
// ---------------------------------------------------------------------------
__global__ __launch_bounds__(128) void conv_qk_kernel(
    const float* __restrict__ pre, const float* __restrict__ cw,
    __hip_bfloat16* __restrict__ out, float scale) {
  const int s = blockIdx.x, h = blockIdx.y, t = threadIdx.x;
  const int c = h * 128 + t;
  const float4 w = *(const float4*)&cw[c * 4];
  float y = pre[(size_t)s * KEY_DIM + c] * w.w;
  if (s >= 1) y += pre[(size_t)(s-1) * KEY_DIM + c] * w.z;
  if (s >= 2) y += pre[(size_t)(s-2) * KEY_DIM + c] * w.y;
  if (s >= 3) y += pre[(size_t)(s-3) * KEY_DIM + c] * w.x;
  float v = y / (1.f + expf(-y));
  float ss = v * v;
  #pragma unroll
  for (int off = 1; off < 64; off <<= 1) ss += __shfl_xor(ss, off, 64);
  __shared__ float red[2];
  if ((t & 63) == 0) red[t >> 6] = ss;
  __syncthreads();
  float inv = scale / sqrtf(red[0] + red[1] + 1e-6f);
  out[((size_t)s * NH + h) * 128 + t] = __float2bfloat16(v * inv);
}

// ---------------------------------------------------------------------------
// conv + SiLU for v
// ---------------------------------------------------------------------------
__global__ __launch_bounds__(256) void conv_v_kernel(
    const float* __restrict__ pre, const float* __restrict__ cw,
    float* __restrict__ out) {
  const int id = blockIdx.x * 256 + threadIdx.x;
  const int s = id >> 11, c = id & 2047;
  const float4 w = *(const float4*)&cw[c * 4];
  float y = pre[id] * w.w;
  if (s >= 1) y += pre[id - VAL_DIM]     * w.z;
  if (s >= 2) y += pre[id - 2*VAL_DIM]   * w.y;
  if (s >= 3) y += pre[id - 3*VAL_DIM]   * w.x;
  out[id] = y / (1.f + expf(-y));
}

// ---------------------------------------------------------------------------
// gl = -exp(A_log)*softplus(a+dt_bias)  (LOG decay), beta = sigmoid(b)
// ---------------------------------------------------------------------------
__global__ __launch_bounds__(256) void gb_kernel(
    const float* __restrict__ a_pre, const float* __restrict__ b_pre,
    const float* __restrict__ A_log, const float* __restrict__ dt_bias,
    float* __restrict__ gl, float* __restrict__ bv) {
  const int id = blockIdx.x * 256 + threadIdx.x;
  const int h = id & 15;
  float av = a_pre[id] + dt_bias[h];
  float sp = av > 20.f ? av : log1pf(expf(av));
  gl[id] = -expf(A_log[h]) * sp;
  bv[id] = 1.f / (1.f + expf(-b_pre[id]));
}

// ---------------------------------------------------------------------------
// Phase A v4: K·K^T via MFMA (k is already bf16 -> numerically equivalent to
// the scalar f32 product of the same values, just reassociated). k staged
// bf16 row-major [j][dk] (direct short8 copies — deletes the old f32
// transpose-scatter). Solve loop unchanged; seeds read k from bf16.
// LDS 151KB -> 134KB.
// ---------------------------------------------------------------------------
__global__ __launch_bounds__(256) void phaseA_kernel(
    const __hip_bfloat16* __restrict__ kn, const float* __restrict__ vc,
    const float* __restrict__ gl, const float* __restrict__ bvv,
    __hip_bfloat16* __restrict__ Wb, __hip_bfloat16* __restrict__ UbT,
    float* __restrict__ Gbuf) {
  const int h = blockIdx.x, c = blockIdx.y, sh = h >> 1;
  const int t = threadIdx.x, lane = t & 63, w = t >> 6;
  const int fm = lane & 15, fq = lane >> 4;
  __shared__ __hip_bfloat16 kch[64][136];  // [j][dk]
  __shared__ float vch[64][132];           // [j][n]
  __shared__ float mm[64][65];
  __shared__ float sol[64][257];           // odd stride: conflict-free per-column
  __shared__ float Gs[64], bet[64], lamB[64];

  {
    const int r = t >> 2, c0 = (t & 3) * 32;
    const __hip_bfloat16* krow = kn + (size_t)(c*64 + r)*KEY_DIM + sh*128 + c0;
    const float* vrow = vc + (size_t)(c*64 + r)*VAL_DIM + h*128 + c0;
    #pragma unroll
    for (int i = 0; i < 4; i++)
      *(short8*)&kch[r][c0 + 8*i] = *(const short8*)&krow[8*i];
    #pragma unroll
    for (int i = 0; i < 8; i++)
      *(float4*)&vch[r][c0 + 4*i] = *(const float4*)&vrow[4*i];
  }
  if (t < 64) {
    float g = gl[(size_t)(c*64 + t)*NVH + h];
    #pragma unroll
    for (int off = 1; off < 64; off <<= 1) {
      float p = __shfl_up(g, off, 64);
      if (t >= off) g += p;
    }
    Gs[t] = g;
    float b = bvv[(size_t)(c*64 + t)*NVH + h];
    bet[t] = b;
    lamB[t] = b * expf(g);
    Gbuf[((size_t)c*NVH + h)*64 + t] = g;
  }
  __syncthreads();

  // mm[j][l] = (l<j) ? bet[j] e^{Gj-Gl} (k_j . k_l) : 0   via MFMA
  {
    f32x4 pacc[4];
    #pragma unroll
    for (int lt = 0; lt < 4; lt++) pacc[lt] = (f32x4){0.f,0.f,0.f,0.f};
    #pragma unroll
    for (int k4 = 0; k4 < 4; k4++) {
      short8 aK = *(const short8*)&kch[16*w + fm][k4*32 + fq*8];
      #pragma unroll
      for (int lt = 0; lt < 4; lt++) {
        short8 bK = *(const short8*)&kch[16*lt + fm][k4*32 + fq*8];
        pacc[lt] = __builtin_amdgcn_mfma_f32_16x16x32_bf16(aK, bK, pacc[lt], 0, 0, 0);
      }
    }
    #pragma unroll
    for (int lt = 0; lt < 4; lt++)
      #pragma unroll
      for (int r2 = 0; r2 < 4; r2++) {
        const int j = 16*w + fq*4 + r2, l = 16*lt + fm;
        mm[j][l] = (l < j) ? bet[j] * expf(Gs[j] - Gs[l]) * pacc[lt][r2] : 0.f;
      }
  }
  __syncthreads();

  {
    const bool isW = t < 128;
    const int col = t & 127;
    for (int j = 0; j < 64; j++) {
      float s0 = isW ? lamB[j] * __bfloat162float(kch[j][col]) : bet[j] * vch[j][col];
      float s1 = 0.f;
      int l = 0;
      for (; l + 1 < j; l += 2) {
        s0 = fmaf(-mm[j][l],   sol[l][t],   s0);
        s1 = fmaf(-mm[j][l+1], sol[l+1][t], s1);
      }
      if (l < j) s0 = fmaf(-mm[j][l], sol[l][t], s0);
      sol[j][t] = s0 + s1;
    }
  }
  if (t < 128) {
    const size_t base = ((size_t)c*NVH + h) * 64 * 128;
    for (int j = 0; j < 64; j++)
      Wb[base + j*128 + t] = __float2bfloat16(sol[j][t]);
  } else {
    const int n = t - 128;
    const size_t ub = (((size_t)c*NVH + h) * 128 + n) * 64;
    for (int j0 = 0; j0 < 64; j0 += 4) {
      union { unsigned long long u; __hip_bfloat16 b[4]; } p;
      #pragma unroll
      for (int i = 0; i < 4; i++) p.b[i] = __float2bfloat16(sol[j0+i][t]);
      *(unsigned long long*)&UbT[ub + j0] = p.u;
    }
  }
}

// ---------------------------------------------------------------------------
// Phase B v9 = v6 (R3's 512-thread, 263-266us, proven) + chunk-parity kT
// double-buffer to close the latent staging race R4 exposed (update reads
// kT[c&1]; stage writes kT[(c+1)&1]). R5 post-mortem: the 1024-thread merge
// regressed 1.77x (VGPR 64 -> spills; per-chunk path scales with per-block
// work at ~25% VALU). phaseB ~10k cy/chunk is this decomposition's floor;
// reverting and moving effort elsewhere.
// ---------------------------------------------------------------------------
__device__ __forceinline__ void bar_lgkm() {
  asm volatile("s_waitcnt lgkmcnt(0)" ::: "memory");
  __builtin_amdgcn_s_barrier();
  asm volatile("" ::: "memory");
}

__global__ __launch_bounds__(512, 2) void phaseB_kernel(
    const __hip_bfloat16* __restrict__ qn, const __hip_bfloat16* __restrict__ kn,
    const __hip_bfloat16* __restrict__ Wb, const __hip_bfloat16* __restrict__ UbT,
    const float* __restrict__ Gbuf,
    __hip_bfloat16* __restrict__ Db, float* __restrict__ obuf) {
  const int bid = blockIdx.x;
  const int h = (bid & 7) | ((bid >> 4) << 3);   // bid, bid+8 -> same h, same XCD
  const int vt = (bid >> 3) & 1;
  const int sh = h >> 1;
  const int t = threadIdx.x, lane = t & 63, w = t >> 6;   // w 0..7
  const int fm = lane & 15, fq = lane >> 4;
  const int jt = w >> 1;          // j-tile (16 rows) for phase-1 / epilogue
  const int nh = w & 1;           // n-half: tj in {2nh, 2nh+1}
  const int dt = w >> 1;          // dk-tile (32 rows) for update/mirror

  __shared__ __hip_bfloat16 S16T[64][136];   // S0 mirror (bf16), [n_loc][dk]
  __shared__ __hip_bfloat16 kT[2][128][72];  // [buf][dk][j] parity dbuf
  __shared__ __hip_bfloat16 dT[64][72];      // e^{G_C-G_j} Delta, [n_loc][j]
  __shared__ float Gs[64];

  // staging assignments (512 threads): k transpose, 4 dk x 4 j per thread
  const int kj = (t & 15) * 4, kd = (t >> 4) * 4;
  const int j0 = 16*jt + fq*4;                    // epilogue rows

  f32x4 Sacc[2][2];
  #pragma unroll
  for (int ti = 0; ti < 2; ti++)
    #pragma unroll
    for (int i = 0; i < 2; i++) Sacc[ti][i] = (f32x4){0.f,0.f,0.f,0.f};
  for (int i = t; i < 64*136/2; i += 512) ((unsigned int*)S16T)[i] = 0;

  ushort4 krg[4];
  short8 Qnext[4], Qcur[4];
  short8 Wnext[4], Wcur[4];
  unsigned long long Unext[2], Ucur[2];
  float gl64;

  auto prefetch = [&](int c) {
    const int cb = (c*NVH + h) * 64;
    const __hip_bfloat16* qbase = qn + (size_t)(c*64 + 16*jt + fm)*KEY_DIM + sh*128 + fq*8;
    #pragma unroll
    for (int k4 = 0; k4 < 4; k4++)
      Qnext[k4] = *(const short8*)&qbase[k4*32];
    #pragma unroll
    for (int jj = 0; jj < 4; jj++)
      krg[jj] = *(const ushort4*)&kn[(size_t)(c*64 + kj + jj)*KEY_DIM + sh*128 + kd];
    #pragma unroll
    for (int k4 = 0; k4 < 4; k4++)
      Wnext[k4] = *(const short8*)&Wb[(size_t)(cb + 16*jt + fm)*128 + k4*32 + fq*8];
    #pragma unroll
    for (int i = 0; i < 2; i++) {
      const int tj = 2*nh + i;
      Unext[i] = *(const unsigned long long*)
          &UbT[(((size_t)c*NVH + h)*128 + vt*64 + 16*tj + fm)*64 + j0];
    }
    if (t < 64) gl64 = Gbuf[(size_t)cb + t];
  };

  auto stage = [&](int buf) {
    if (t < 64) Gs[t] = gl64;
    union { ushort4 v[4]; unsigned short u[16]; } kk;
    #pragma unroll
    for (int jj = 0; jj < 4; jj++) kk.v[jj] = krg[jj];
    #pragma unroll
    for (int dd = 0; dd < 4; dd++) {
      union { unsigned short u[4]; unsigned long long q; } p;
      #pragma unroll
      for (int jj = 0; jj < 4; jj++) p.u[jj] = kk.u[jj*4 + dd];
      *(unsigned long long*)&kT[buf][kd + dd][kj] = p.q;
    }
  };

  prefetch(0);
  #pragma unroll
  for (int k4 = 0; k4 < 4; k4++) { Qcur[k4] = Qnext[k4]; Wcur[k4] = Wnext[k4]; }
  #pragma unroll
  for (int i = 0; i < 2; i++) Ucur[i] = Unext[i];
  bar_lgkm();               // S16T zero-init visible
  stage(0);
  bar_lgkm();               // chunk-0 staging + Gs visible

  for (int c = 0; c < NCH; c++) {
    // issue prefetch for c+1 (independent; drains at the reg-copy at chunk end)
    prefetch(c + 1 < NCH ? c + 1 : 0);

    // (1)+(2): X = W S0, opart_raw = q S0   (wave covers j-tile jt x n-half nh)
    f32x4 aX[2], aO[2];
    #pragma unroll
    for (int i = 0; i < 2; i++) {
      aX[i] = (f32x4){0.f,0.f,0.f,0.f};
      aO[i] = (f32x4){0.f,0.f,0.f,0.f};
    }
    __builtin_amdgcn_s_setprio(1);
    #pragma unroll
    for (int k4 = 0; k4 < 4; k4++) {
      #pragma unroll
      for (int i = 0; i < 2; i++) {
        const int tj = 2*nh + i;
        short8 b = *(const short8*)&S16T[16*tj + fm][k4*32 + fq*8];
        aX[i] = __builtin_amdgcn_mfma_f32_16x16x32_bf16(Wcur[k4], b, aX[i], 0, 0, 0);
        aO[i] = __builtin_amdgcn_mfma_f32_16x16x32_bf16(Qcur[k4], b, aO[i], 0, 0, 0);
      }
    }
    __builtin_amdgcn_s_setprio(0);
    // epilogue: Delta, dT, stores. o_intra[j] = e^{G_j} (q_j . S0) -> scale aO.
    const int cb = (c*NVH + h) * 64;
    const float gC = Gs[63];
    float er[4], os[4];
    #pragma unroll
    for (int r2 = 0; r2 < 4; r2++) {
      const float gj = Gs[j0 + r2];
      os[r2] = expf(gj);
      er[r2] = expf(gC - gj);
    }
    #pragma unroll
    for (int i = 0; i < 2; i++) {
      const int tj = 2*nh + i;
      const int n = 16*tj + fm;
      union { unsigned long long u; __hip_bfloat16 b[4]; } u4;
      u4.u = Ucur[i];
      union { __hip_bfloat16 b[4]; unsigned long long u; } pd;
      #pragma unroll
      for (int r2 = 0; r2 < 4; r2++) {
        const int j = j0 + r2;
        float d = __bfloat162float(u4.b[r2]) - aX[i][r2];
        Db[(size_t)(cb + j)*128 + vt*64 + n] = __float2bfloat16(d);
        pd.b[r2] = __float2bfloat16(d * er[r2]);
        obuf[((size_t)(c*64 + j)*NVH + h)*128 + vt*64 + n] = aO[i][r2] * os[r2];
      }
      *(unsigned long long*)&dT[n][j0] = pd.u;
    }
    // decay S
    const float lamC = expf(gC);
    #pragma unroll
    for (int ti = 0; ti < 2; ti++)
      #pragma unroll
      for (int i = 0; i < 2; i++)
        #pragma unroll
        for (int r2 = 0; r2 < 4; r2++) Sacc[ti][i][r2] *= lamC;
    // barrier A: dT visible; all phase-1 S16T reads + epilogue Gs reads done.
    bar_lgkm();
    // (3): S += K^T dT'   (wave covers dk-tile dt x n-half nh; reads kT[c&1])
    __builtin_amdgcn_s_setprio(1);
    #pragma unroll
    for (int ti = 0; ti < 2; ti++) {
      const int m0 = 32*dt + 16*ti;
      #pragma unroll
      for (int kk0 = 0; kk0 < 64; kk0 += 32) {
        short8 aK = *(const short8*)&kT[c & 1][m0 + fm][kk0 + fq*8];
        #pragma unroll
        for (int i = 0; i < 2; i++) {
          const int tj = 2*nh + i;
          short8 bD = *(const short8*)&dT[16*tj + fm][kk0 + fq*8];
          Sacc[ti][i] = __builtin_amdgcn_mfma_f32_16x16x32_bf16(aK, bD, Sacc[ti][i], 0, 0, 0);
        }
      }
    }
    __builtin_amdgcn_s_setprio(0);
    // refresh bf16 mirror (cols 32dt..32dt+32, rows n in this wave's n-half)
    #pragma unroll
    for (int ti = 0; ti < 2; ti++) {
      const int dk0 = 32*dt + 16*ti + fq*4;
      #pragma unroll
      for (int i = 0; i < 2; i++) {
        const int tj = 2*nh + i;
        const int n = 16*tj + fm;
        union { __hip_bfloat16 b[4]; unsigned long long u; } ps;
        #pragma unroll
        for (int r2 = 0; r2 < 4; r2++) ps.b[r2] = __float2bfloat16(Sacc[ti][i][r2]);
        *(unsigned long long*)&S16T[n][dk0] = ps.u;
      }
    }
    // stage c+1 k -> kT[(c+1)&1] (other buffer than update reads); regs -> cur
    stage((c + 1) & 1);
    #pragma unroll
    for (int k4 = 0; k4 < 4; k4++) { Qcur[k4] = Qnext[k4]; Wcur[k4] = Wnext[k4]; }
    #pragma unroll
    for (int i = 0; i < 2; i++) Ucur[i] = Unext[i];
    // barrier B: S16T mirror + Gs + kT staging visible for chunk c+1
    bar_lgkm();
  }
}

// ---------------------------------------------------------------------------
// Phase C v3: both GEMMs via MFMA. Stage 1: P[j][l] = tril(e^{Gj-Gl} q_j.k_l)
// (MFMA over dk, f32 acc, exp/causal on acc, P -> bf16 LDS). Stage 2:
// O[j][n] += sum_l P[j][l] D[l][n] (MFMA over l, B = D^T staged at load).
// One barrier total: Pbf rows are wave-local (written+read by wave w);
// dchT/kch/qch staged before the barrier. LDS 103KB -> 63KB (2 blocks/CU).
// New rounding: P in bf16 (D was already bf16) — est +0.02-0.03 absmax.
// ---------------------------------------------------------------------------
__global__ __launch_bounds__(256) void phaseC_kernel(
    const __hip_bfloat16* __restrict__ qn, const __hip_bfloat16* __restrict__ kn,
    const float* __restrict__ Gbuf, const __hip_bfloat16* __restrict__ Db,
    float* __restrict__ obuf) {
  const int h = blockIdx.x, c = blockIdx.y, sh = h >> 1;
  const int t = threadIdx.x, lane = t & 63, w = t >> 6;
  const int fm = lane & 15, fq = lane >> 4;
  __shared__ __hip_bfloat16 qch[64][136];   // [j][dk]
  __shared__ __hip_bfloat16 kch[64][136];   // [l][dk]
  __shared__ __hip_bfloat16 dchT[128][72];  // [n][l]
  __shared__ __hip_bfloat16 Pbf[64][72];    // [j][l]
  __shared__ float Gs[64];

  {
    const int r = t >> 2, c0 = (t & 3) * 32;
    const __hip_bfloat16* qrow = qn + (size_t)(c*64 + r)*KEY_DIM + sh*128 + c0;
    const __hip_bfloat16* krow = kn + (size_t)(c*64 + r)*KEY_DIM + sh*128 + c0;
    #pragma unroll
    for (int i = 0; i < 4; i++) {
      *(short8*)&qch[r][c0 + 8*i] = *(const short8*)&qrow[8*i];
      *(short8*)&kch[r][c0 + 8*i] = *(const short8*)&krow[8*i];
    }
    const __hip_bfloat16* drow = Db + ((size_t)c*NVH + h)*64*128 + (size_t)r*128 + c0;
    #pragma unroll
    for (int i = 0; i < 4; i++) {
      union { short8 s; unsigned short u[8]; } dv;
      dv.s = *(const short8*)&drow[8*i];
      #pragma unroll
      for (int e = 0; e < 8; e++)
        *(unsigned short*)&dchT[c0 + 8*i + e][r] = dv.u[e];
    }
  }
  if (t < 64) Gs[t] = Gbuf[((size_t)c*NVH + h)*64 + t];
  __syncthreads();

  // stage 1: P = tril(e^{Gj-Gl} * q k^T), wave w owns j-tile w
  {
    f32x4 pacc[4];
    #pragma unroll
    for (int lt = 0; lt < 4; lt++) pacc[lt] = (f32x4){0.f,0.f,0.f,0.f};
    #pragma unroll
    for (int k4 = 0; k4 < 4; k4++) {
      short8 aQ = *(const short8*)&qch[16*w + fm][k4*32 + fq*8];
      #pragma unroll
      for (int lt = 0; lt < 4; lt++) {
        short8 bK = *(const short8*)&kch[16*lt + fm][k4*32 + fq*8];
        pacc[lt] = __builtin_amdgcn_mfma_f32_16x16x32_bf16(aQ, bK, pacc[lt], 0, 0, 0);
      }
    }
    #pragma unroll
    for (int lt = 0; lt < 4; lt++)
      #pragma unroll
      for (int r2 = 0; r2 < 4; r2++) {
        const int j = 16*w + fq*4 + r2, l = 16*lt + fm;
        float v = (l <= j) ? expf(Gs[j] - Gs[l]) * pacc[lt][r2] : 0.f;
        Pbf[j][l] = __float2bfloat16(v);
      }
  }
  // no barrier: Pbf rows [16w,16w+16) are written and read by the same wave

  // stage 2: O[j][n] += P . D  (contraction over l, 2 k-steps of 32)
  {
    f32x4 oacc[8];
    #pragma unroll
    for (int nt = 0; nt < 8; nt++) oacc[nt] = (f32x4){0.f,0.f,0.f,0.f};
    #pragma unroll
    for (int ks = 0; ks < 2; ks++) {
      short8 aP = *(const short8*)&Pbf[16*w + fm][ks*32 + fq*8];
      #pragma unroll
      for (int nt = 0; nt < 8; nt++) {
        short8 bD = *(const short8*)&dchT[16*nt + fm][ks*32 + fq*8];
        oacc[nt] = __builtin_amdgcn_mfma_f32_16x16x32_bf16(aP, bD, oacc[nt], 0, 0, 0);
      }
    }
    #pragma unroll
    for (int nt = 0; nt < 8; nt++)
      #pragma unroll
      for (int r2 = 0; r2 < 4; r2++) {
        const int j = 16*w + fq*4 + r2, n = 16*nt + fm;
        float* p = &obuf[((size_t)(c*64 + j)*NVH + h)*128 + n];
        *p += oacc[nt][r2];
      }
  }
}

// ---------------------------------------------------------------------------
// Gated RMSNorm -> bf16
// ---------------------------------------------------------------------------
__global__ __launch_bounds__(128) void norm_kernel(
    const float* __restrict__ o, const float* __restrict__ gate,
    const float* __restrict__ w_norm, __hip_bfloat16* __restrict__ og) {
  const int s = blockIdx.x, h = blockIdx.y, t = threadIdx.x;
  const size_t idx = (size_t)s * VAL_DIM + h * 128 + t;
  float gt = gate[idx];
  float val = o[idx] * (gt / (1.f + expf(-gt)));
  float ss = val * val;
  #pragma unroll
  for (int off = 1; off < 64; off <<= 1) ss += __shfl_xor(ss, off, 64);
  __shared__ float red[2];
  if ((t & 63) == 0) red[t >> 6] = ss;
  __syncthreads();
  float ms = (red[0] + red[1]) * (1.f / 128.f);
  og[idx] = __float2bfloat16(val * (1.f / sqrtf(ms + 1e-6f)) * w_norm[t]);
}

// ---------------------------------------------------------------------------
extern "C" void kernel_launch(void* const* d_in, const int* in_sizes, int n_in,
                              void* d_out, int out_size, void* d_ws, size_t ws_size,
                              hipStream_t stream) {
  const float* x       = (const float*)d_in[0];
  const float* Wq      = (const float*)d_in[1];
  const float* Wk      = (const float*)d_in[2];
  const float* Wv      = (const float*)d_in[3];
  const float* Wa      = (const float*)d_in[4];
  const float* Wb_     = (const float*)d_in[5];
  const float* Wg      = (const float*)d_in[6];
  const float* Wo      = (const float*)d_in[7];
  const float* conv_q  = (const float*)d_in[8];
  const float* conv_k  = (const float*)d_in[9];
  const float* conv_v  = (const float*)d_in[10];
  const float* A_log   = (const float*)d_in[11];
  const float* dt_bias = (const float*)d_in[12];
  const float* w_norm  = (const float*)d_in[13];
  float* out = (float*)d_out;

  const size_t QK = (size_t)S_LEN * KEY_DIM;   // 4.19M
  const size_t SV = (size_t)S_LEN * VAL_DIM;   // 8.39M
  const size_t SM = (size_t)S_LEN * NVH;       // 65536

  float* W = (float*)d_ws;
  float* q_pre = W;
  float* k_pre = q_pre + QK;
  float* v_pre = k_pre + QK;       // SV floats; later: UbT (bf16) | Db (bf16)
  float* qn    = v_pre + SV;       // bf16 (slot kept float-sized)
  float* kn    = qn + QK;          // bf16; later: ogb
  float* vcb   = kn + QK;          // SV floats; later: obuf
  float* a_pre = vcb + SV;
  float* b_pre = a_pre + SM;
  float* glb   = b_pre + SM;
  float* beta  = glb + SM;
  float* Gbuf  = beta + SM;        // NCH*NVH*64 = 65536
  __hip_bfloat16* xb = (__hip_bfloat16*)(Gbuf + SM);  // 8.39M bf16; later: Wb
  __hip_bfloat16* wb = xb + SV;                       // up to 4.19M bf16

  float* gate = q_pre;             // after convs
  float* obuf = vcb;               // after phase A
  __hip_bfloat16* qnb = (__hip_bfloat16*)qn;
  __hip_bfloat16* knb = (__hip_bfloat16*)kn;
  __hip_bfloat16* ogb = (__hip_bfloat16*)kn;  // norm output (after phaseC)
  __hip_bfloat16* Wbb = xb;                   // after gate gemm
  __hip_bfloat16* UbT = (__hip_bfloat16*)v_pre;
  __hip_bfloat16* Db  = (__hip_bfloat16*)(v_pre + SV/2);

  const int NC = 256 * 4;
  cast_f2b<<<(S_LEN*HID)/NC, 256, 0, stream>>>(x, xb, S_LEN*HID);

  cast_f2b<<<(KEY_DIM*HID)/NC, 256, 0, stream>>>(Wq, wb, KEY_DIM*HID);
  gemm_bf16_bt<<<dim3(KEY_DIM/128, S_LEN/128), 256, 0, stream>>>(xb, wb, q_pre, S_LEN, KEY_DIM, HID);
  cast_f2b<<<(KEY_DIM*HID)/NC, 256, 0, stream>>>(Wk, wb, KEY_DIM*HID);
  gemm_bf16_bt<<<dim3(KEY_DIM/128, S_LEN/128), 256, 0, stream>>>(xb, wb, k_pre, S_LEN, KEY_DIM, HID);
  cast_f2b<<<(VAL_DIM*HID)/NC, 256, 0, stream>>>(Wv, wb, VAL_DIM*HID);
  gemm_bf16_bt<<<dim3(VAL_DIM/128, S_LEN/128), 256, 0, stream>>>(xb, wb, v_pre, S_LEN, VAL_DIM, HID);
  gemm_bt<<<dim3(1, S_LEN/64), 256, 0, stream>>>(x, Wa, a_pre, S_LEN, NVH, HID);
  gemm_bt<<<dim3(1, S_LEN/64), 256, 0, stream>>>(x, Wb_, b_pre, S_LEN, NVH, HID);

  conv_qk_kernel<<<dim3(S_LEN, NH), 128, 0, stream>>>(q_pre, conv_q, qnb, SCALE_Q);
  conv_qk_kernel<<<dim3(S_LEN, NH), 128, 0, stream>>>(k_pre, conv_k, knb, 1.f);
  conv_v_kernel<<<(S_LEN*VAL_DIM)/256, 256, 0, stream>>>(v_pre, conv_v, vcb);
  gb_kernel<<<(S_LEN*NVH)/256, 256, 0, stream>>>(a_pre, b_pre, A_log, dt_bias, glb, beta);

  cast_f2b<<<(VAL_DIM*HID)/NC, 256, 0, stream>>>(Wg, wb, VAL_DIM*HID);
  gemm_bf16_bt<<<dim3(VAL_DIM/128, S_LEN/128), 256, 0, stream>>>(xb, wb, gate, S_LEN, VAL_DIM, HID);

  // chunked delta-rule scan
  phaseA_kernel<<<dim3(NVH, NCH), 256, 0, stream>>>(knb, vcb, glb, beta, Wbb, UbT, Gbuf);
  phaseB_kernel<<<2*NVH, 512, 0, stream>>>(qnb, knb, Wbb, UbT, Gbuf, Db, obuf);
  phaseC_kernel<<<dim3(NVH, NCH), 256, 0, stream>>>(qnb, knb, Gbuf, Db, obuf);

  norm_kernel<<<dim3(S_LEN, NVH), 128, 0, stream>>>(obuf, gate, w_norm, ogb);

  cast_f2b<<<(HID*VAL_DIM)/NC, 256, 0, stream>>>(Wo, wb, HID*VAL_DIM);
  gemm_bf16_bt<<<dim3(HID/128, S_LEN/128), 256, 0, stream>>>(ogb, wb, out, S_LEN, HID, VAL_DIM);
}

// Round 7
// 1000.205 us; speedup vs baseline: 1.4602x; 1.2007x over previous
//
#include <hip/hip_runtime.h>
#include <hip/hip_bf16.h>
#include <math.h>

#define S_LEN 4096
#define HID   2048
#define NH    8
#define NVH   16
#define DK    128
#define DV    128
#define KEY_DIM  (NH*DK)    // 1024
#define VAL_DIM  (NVH*DV)   // 2048
#define NPROJ 6144          // fused q|k|v|gate projection width
#define SCALE_Q  0.08838834764831845f  // 128^-0.5
#define CCH 64              // chunk length
#define NCH (S_LEN/CCH)     // 64 chunks

typedef __attribute__((ext_vector_type(8))) short short8;   // 8 bf16
typedef __attribute__((ext_vector_type(4))) float f32x4;

// ---------------------------------------------------------------------------
// float -> bf16 cast (single src)
// ---------------------------------------------------------------------------
__global__ __launch_bounds__(256) void cast_f2b(
    const float* __restrict__ in, __hip_bfloat16* __restrict__ out, int n) {
  int i = (blockIdx.x * 256 + threadIdx.x) * 4;
  if (i >= n) return;
  float4 v = *(const float4*)&in[i];
  union { __hip_bfloat16 b[4]; short4 s; } u;
  u.b[0] = __float2bfloat16(v.x); u.b[1] = __float2bfloat16(v.y);
  u.b[2] = __float2bfloat16(v.z); u.b[3] = __float2bfloat16(v.w);
  *(short4*)&out[i] = u.s;
}

// ---------------------------------------------------------------------------
// 5-weight cast into one contiguous bf16 arena: [Wq|Wk|Wv|Wg|Wo]
// boundaries (elems): 0, 2097152, 4194304, 8388608, 12582912, 16777216
// ---------------------------------------------------------------------------
__global__ __launch_bounds__(256) void cast5(
    const float* __restrict__ w0, const float* __restrict__ w1,
    const float* __restrict__ w2, const float* __restrict__ w3,
    const float* __restrict__ w4, __hip_bfloat16* __restrict__ dst) {
  int i = (blockIdx.x * 256 + threadIdx.x) * 4;
  const float* src; int off;
  if      (i <  2097152) { src = w0; off = 0; }
  else if (i <  4194304) { src = w1; off = 2097152; }
  else if (i <  8388608) { src = w2; off = 4194304; }
  else if (i < 12582912) { src = w3; off = 8388608; }
  else                   { src = w4; off = 12582912; }
  float4 v = *(const float4*)&src[i - off];
  union { __hip_bfloat16 b[4]; short4 s; } u;
  u.b[0] = __float2bfloat16(v.x); u.b[1] = __float2bfloat16(v.y);
  u.b[2] = __float2bfloat16(v.z); u.b[3] = __float2bfloat16(v.w);
  *(short4*)&dst[i] = u.s;
}

// ---------------------------------------------------------------------------
// bf16 MFMA GEMM: C[M,N](fp32) = A[M,K] @ B[N,K]^T  (m97 structure)
// ---------------------------------------------------------------------------
__device__ __forceinline__ void lds_load16(const __hip_bfloat16* g,
                                           __hip_bfloat16* l) {
  __builtin_amdgcn_global_load_lds(
      (const __attribute__((address_space(1))) unsigned int*)g,
      (__attribute__((address_space(3))) unsigned int*)l, 16, 0, 0);
}

__global__ __launch_bounds__(256) void gemm_bf16_bt(
    const __hip_bfloat16* __restrict__ A, const __hip_bfloat16* __restrict__ B,
    float* __restrict__ C, int M, int N, int K) {
  __shared__ __hip_bfloat16 sA[128 * 32];
  __shared__ __hip_bfloat16 sB[128 * 32];
  const int t = threadIdx.x;
  const int wave = t >> 6, lane = t & 63;
  const int bm = blockIdx.y, bn = blockIdx.x;
  const int wm = (wave & 1) * 64, wn = (wave >> 1) * 64;

  f32x4 zero = {0.f, 0.f, 0.f, 0.f};
  f32x4 acc[4][4];
  #pragma unroll
  for (int i = 0; i < 4; i++)
    #pragma unroll
    for (int j = 0; j < 4; j++) acc[i][j] = zero;

  const int r0 = t >> 2,        c0 = (t & 3) * 8;
  const int r1 = (256 + t) >> 2, c1 = ((256 + t) & 3) * 8;
  const __hip_bfloat16* gA0 = A + (size_t)(bm * 128 + r0) * K + c0;
  const __hip_bfloat16* gA1 = A + (size_t)(bm * 128 + r1) * K + c1;
  const __hip_bfloat16* gB0 = B + (size_t)(bn * 128 + r0) * K + c0;
  const __hip_bfloat16* gB1 = B + (size_t)(bn * 128 + r1) * K + c1;
  __hip_bfloat16* lA0 = sA + (size_t)(wave * 64) * 8;
  __hip_bfloat16* lA1 = sA + (size_t)(256 + wave * 64) * 8;
  __hip_bfloat16* lB0 = sB + (size_t)(wave * 64) * 8;
  __hip_bfloat16* lB1 = sB + (size_t)(256 + wave * 64) * 8;

  const int fm = lane & 15, fk = (lane >> 4) * 8;

  for (int k0 = 0; k0 < K; k0 += 32) {
    lds_load16(gA0, lA0); lds_load16(gA1, lA1);
    lds_load16(gB0, lB0); lds_load16(gB1, lB1);
    gA0 += 32; gA1 += 32; gB0 += 32; gB1 += 32;
    __syncthreads();
    short8 a[4], b[4];
    #pragma unroll
    for (int i = 0; i < 4; i++)
      a[i] = *(const short8*)&sA[(size_t)(wm + i * 16 + fm) * 32 + fk];
    #pragma unroll
    for (int j = 0; j < 4; j++)
      b[j] = *(const short8*)&sB[(size_t)(wn + j * 16 + fm) * 32 + fk];
    #pragma unroll
    for (int i = 0; i < 4; i++)
      #pragma unroll
      for (int j = 0; j < 4; j++)
        acc[i][j] = __builtin_amdgcn_mfma_f32_16x16x32_bf16(a[i], b[j], acc[i][j], 0, 0, 0);
    __syncthreads();
  }
  #pragma unroll
  for (int i = 0; i < 4; i++) {
    #pragma unroll
    for (int j = 0; j < 4; j++) {
      int col = bn * 128 + wn + j * 16 + (lane & 15);
      int rw0 = bm * 128 + wm + i * 16 + (lane >> 4) * 4;
      #pragma unroll
      for (int r = 0; r < 4; r++)
        C[(size_t)(rw0 + r) * N + col] = acc[i][j][r];
    }
  }
}

// ---------------------------------------------------------------------------
// fp32 GEMM for the tiny N=16 projections: one launch does BOTH Wa and Wb
// (blockIdx.x selects). Was 2 launches at 25% chip each.
// ---------------------------------------------------------------------------
__global__ __launch_bounds__(256) void gemm_bt2(
    const float* __restrict__ A, const float* __restrict__ Ba,
    const float* __restrict__ Bb, float* __restrict__ Ca,
    float* __restrict__ Cb, int K) {
  const float* B = blockIdx.x == 0 ? Ba : Bb;
  float* C       = blockIdx.x == 0 ? Ca : Cb;
  const int N = NVH;  // 16
  __shared__ float As[16][68];
  __shared__ float Bs[16][68];
  const int bm = blockIdx.y;
  const int t = threadIdx.x;
  const int tx = t & 15, ty = t >> 4;
  const int lrow = t >> 2;
  const int lk0  = (t & 3) * 4;
  const int arow = bm * 64 + lrow;
  const bool bvalid = lrow < N;

  float acc[4][4];
  #pragma unroll
  for (int i = 0; i < 4; i++)
    #pragma unroll
    for (int j = 0; j < 4; j++) acc[i][j] = 0.f;

  for (int k0 = 0; k0 < K; k0 += 16) {
    float4 av = *(const float4*)&A[(size_t)arow * K + k0 + lk0];
    float4 bv = bvalid ? *(const float4*)&B[(size_t)lrow * K + k0 + lk0]
                       : make_float4(0.f, 0.f, 0.f, 0.f);
    As[lk0+0][lrow] = av.x; As[lk0+1][lrow] = av.y;
    As[lk0+2][lrow] = av.z; As[lk0+3][lrow] = av.w;
    Bs[lk0+0][lrow] = bv.x; Bs[lk0+1][lrow] = bv.y;
    Bs[lk0+2][lrow] = bv.z; Bs[lk0+3][lrow] = bv.w;
    __syncthreads();
    #pragma unroll
    for (int kk = 0; kk < 16; kk++) {
      float4 a = *(const float4*)&As[kk][ty * 4];
      float4 b = *(const float4*)&Bs[kk][tx * 4];
      float ar[4] = {a.x, a.y, a.z, a.w};
      float br[4] = {b.x, b.y, b.z, b.w};
      #pragma unroll
      for (int i = 0; i < 4; i++)
        #pragma unroll
        for (int j = 0; j < 4; j++) acc[i][j] += ar[i] * br[j];
    }
    __syncthreads();
  }
  #pragma unroll
  for (int i = 0; i < 4; i++) {
    int r = bm * 64 + ty * 4 + i;
    #pragma unroll
    for (int j = 0; j < 4; j++) {
      int c = tx * 4 + j;
      if (c < N) C[(size_t)r * N + c] = acc[i][j];
    }
  }
}

// ---------------------------------------------------------------------------
// conv + SiLU + l2norm for q AND k in one launch (blockIdx.y: 0-7 q, 8-15 k).
// pre is the fused [S][6144] projection buffer (q cols 0.., k cols 1024..).
// ---------------------------------------------------------------------------
__global__ __launch_bounds__(128) void conv_qk_kernel(
    const float* __restrict__ pre, const float* __restrict__ cwq,
    const float* __restrict__ cwk, __hip_bfloat16* __restrict__ qn,
    __hip_bfloat16* __restrict__ kn) {
  const int s = blockIdx.x, y = blockIdx.y, t = threadIdx.x;
  const bool isq = y < 8;
  const int h = isq ? y : y - 8;
  const int ch = h * 128 + t;
  const float* cw = isq ? cwq : cwk;
  const int col = (isq ? 0 : 1024) + ch;
  const float4 w = *(const float4*)&cw[ch * 4];
  const size_t base = (size_t)s * NPROJ + col;
  float v0 = pre[base] * w.w;
  if (s >= 1) v0 += pre[base - NPROJ]     * w.z;
  if (s >= 2) v0 += pre[base - 2*NPROJ]   * w.y;
  if (s >= 3) v0 += pre[base - 3*NPROJ]   * w.x;
  float v = v0 / (1.f + expf(-v0));
  float ss = v * v;
  #pragma unroll
  for (int off = 1; off < 64; off <<= 1) ss += __shfl_xor(ss, off, 64);
  __shared__ float red[2];
  if ((t & 63) == 0) red[t >> 6] = ss;
  __syncthreads();
  const float scale = isq ? SCALE_Q : 1.f;
  float inv = scale / sqrtf(red[0] + red[1] + 1e-6f);
  __hip_bfloat16* out = isq ? qn : kn;
  out[((size_t)s * NH + h) * 128 + t] = __float2bfloat16(v * inv);
}

// ---------------------------------------------------------------------------
// conv + SiLU for v (reads fused pre, cols 2048..4095)
// ---------------------------------------------------------------------------
__global__ __launch_bounds__(256) void conv_v_kernel(
    const float* __restrict__ pre, const float* __restrict__ cw,
    float* __restrict__ out) {
  const int id = blockIdx.x * 256 + threadIdx.x;
  const int s = id >> 11, c = id & 2047;
  const float4 w = *(const float4*)&cw[c * 4];
  const size_t base = (size_t)s * NPROJ + 2048 + c;
  float y = pre[base] * w.w;
  if (s >= 1) y += pre[base - NPROJ]     * w.z;
  if (s >= 2) y += pre[base - 2*NPROJ]   * w.y;
  if (s >= 3) y += pre[base - 3*NPROJ]   * w.x;
  out[id] = y / (1.f + expf(-y));
}

// ---------------------------------------------------------------------------
// gl = -exp(A_log)*softplus(a+dt_bias)  (LOG decay), beta = sigmoid(b)
// ---------------------------------------------------------------------------
__global__ __launch_bounds__(256) void gb_kernel(
    const float* __restrict__ a_pre, const float* __restrict__ b_pre,
    const float* __restrict__ A_log, const float* __restrict__ dt_bias,
    float* __restrict__ gl, float* __restrict__ bv) {
  const int id = blockIdx.x * 256 + threadIdx.x;
  const int h = id & 15;
  float av = a_pre[id] + dt_bias[h];
  float sp = av > 20.f ? av : log1pf(expf(av));
  gl[id] = -expf(A_log[h]) * sp;
  bv[id] = 1.f / (1.f + expf(-b_pre[id]));
}

// ---------------------------------------------------------------------------
// Phase A v4 (unchanged from R6): K.K^T via MFMA, bf16 k staging
// ---------------------------------------------------------------------------
__global__ __launch_bounds__(256) void phaseA_kernel(
    const __hip_bfloat16* __restrict__ kn, const float* __restrict__ vc,
    const float* __restrict__ gl, const float* __restrict__ bvv,
    __hip_bfloat16* __restrict__ Wb, __hip_bfloat16* __restrict__ UbT,
    float* __restrict__ Gbuf) {
  const int h = blockIdx.x, c = blockIdx.y, sh = h >> 1;
  const int t = threadIdx.x, lane = t & 63, w = t >> 6;
  const int fm = lane & 15, fq = lane >> 4;
  __shared__ __hip_bfloat16 kch[64][136];  // [j][dk]
  __shared__ float vch[64][132];           // [j][n]
  __shared__ float mm[64][65];
  __shared__ float sol[64][257];           // odd stride: conflict-free per-column
  __shared__ float Gs[64], bet[64], lamB[64];

  {
    const int r = t >> 2, c0 = (t & 3) * 32;
    const __hip_bfloat16* krow = kn + (size_t)(c*64 + r)*KEY_DIM + sh*128 + c0;
    const float* vrow = vc + (size_t)(c*64 + r)*VAL_DIM + h*128 + c0;
    #pragma unroll
    for (int i = 0; i < 4; i++)
      *(short8*)&kch[r][c0 + 8*i] = *(const short8*)&krow[8*i];
    #pragma unroll
    for (int i = 0; i < 8; i++)
      *(float4*)&vch[r][c0 + 4*i] = *(const float4*)&vrow[4*i];
  }
  if (t < 64) {
    float g = gl[(size_t)(c*64 + t)*NVH + h];
    #pragma unroll
    for (int off = 1; off < 64; off <<= 1) {
      float p = __shfl_up(g, off, 64);
      if (t >= off) g += p;
    }
    Gs[t] = g;
    float b = bvv[(size_t)(c*64 + t)*NVH + h];
    bet[t] = b;
    lamB[t] = b * expf(g);
    Gbuf[((size_t)c*NVH + h)*64 + t] = g;
  }
  __syncthreads();

  // mm[j][l] = (l<j) ? bet[j] e^{Gj-Gl} (k_j . k_l) : 0   via MFMA
  {
    f32x4 pacc[4];
    #pragma unroll
    for (int lt = 0; lt < 4; lt++) pacc[lt] = (f32x4){0.f,0.f,0.f,0.f};
    #pragma unroll
    for (int k4 = 0; k4 < 4; k4++) {
      short8 aK = *(const short8*)&kch[16*w + fm][k4*32 + fq*8];
      #pragma unroll
      for (int lt = 0; lt < 4; lt++) {
        short8 bK = *(const short8*)&kch[16*lt + fm][k4*32 + fq*8];
        pacc[lt] = __builtin_amdgcn_mfma_f32_16x16x32_bf16(aK, bK, pacc[lt], 0, 0, 0);
      }
    }
    #pragma unroll
    for (int lt = 0; lt < 4; lt++)
      #pragma unroll
      for (int r2 = 0; r2 < 4; r2++) {
        const int j = 16*w + fq*4 + r2, l = 16*lt + fm;
        mm[j][l] = (l < j) ? bet[j] * expf(Gs[j] - Gs[l]) * pacc[lt][r2] : 0.f;
      }
  }
  __syncthreads();

  {
    const bool isW = t < 128;
    const int col = t & 127;
    for (int j = 0; j < 64; j++) {
      float s0 = isW ? lamB[j] * __bfloat162float(kch[j][col]) : bet[j] * vch[j][col];
      float s1 = 0.f;
      int l = 0;
      for (; l + 1 < j; l += 2) {
        s0 = fmaf(-mm[j][l],   sol[l][t],   s0);
        s1 = fmaf(-mm[j][l+1], sol[l+1][t], s1);
      }
      if (l < j) s0 = fmaf(-mm[j][l], sol[l][t], s0);
      sol[j][t] = s0 + s1;
    }
  }
  if (t < 128) {
    const size_t base = ((size_t)c*NVH + h) * 64 * 128;
    for (int j = 0; j < 64; j++)
      Wb[base + j*128 + t] = __float2bfloat16(sol[j][t]);
  } else {
    const int n = t - 128;
    const size_t ub = (((size_t)c*NVH + h) * 128 + n) * 64;
    for (int j0 = 0; j0 < 64; j0 += 4) {
      union { unsigned long long u; __hip_bfloat16 b[4]; } p;
      #pragma unroll
      for (int i = 0; i < 4; i++) p.b[i] = __float2bfloat16(sol[j0+i][t]);
      *(unsigned long long*)&UbT[ub + j0] = p.u;
    }
  }
}

// ---------------------------------------------------------------------------
// Phase B v9 (unchanged from R6, 270us proven): 512 threads, kT parity dbuf
// ---------------------------------------------------------------------------
__device__ __forceinline__ void bar_lgkm() {
  asm volatile("s_waitcnt lgkmcnt(0)" ::: "memory");
  __builtin_amdgcn_s_barrier();
  asm volatile("" ::: "memory");
}

__global__ __launch_bounds__(512, 2) void phaseB_kernel(
    const __hip_bfloat16* __restrict__ qn, const __hip_bfloat16* __restrict__ kn,
    const __hip_bfloat16* __restrict__ Wb, const __hip_bfloat16* __restrict__ UbT,
    const float* __restrict__ Gbuf,
    __hip_bfloat16* __restrict__ Db, float* __restrict__ obuf) {
  const int bid = blockIdx.x;
  const int h = (bid & 7) | ((bid >> 4) << 3);   // bid, bid+8 -> same h, same XCD
  const int vt = (bid >> 3) & 1;
  const int sh = h >> 1;
  const int t = threadIdx.x, lane = t & 63, w = t >> 6;   // w 0..7
  const int fm = lane & 15, fq = lane >> 4;
  const int jt = w >> 1;          // j-tile (16 rows) for phase-1 / epilogue
  const int nh = w & 1;           // n-half: tj in {2nh, 2nh+1}
  const int dt = w >> 1;          // dk-tile (32 rows) for update/mirror

  __shared__ __hip_bfloat16 S16T[64][136];   // S0 mirror (bf16), [n_loc][dk]
  __shared__ __hip_bfloat16 kT[2][128][72];  // [buf][dk][j] parity dbuf
  __shared__ __hip_bfloat16 dT[64][72];      // e^{G_C-G_j} Delta, [n_loc][j]
  __shared__ float Gs[64];

  const int kj = (t & 15) * 4, kd = (t >> 4) * 4;
  const int j0 = 16*jt + fq*4;                    // epilogue rows

  f32x4 Sacc[2][2];
  #pragma unroll
  for (int ti = 0; ti < 2; ti++)
    #pragma unroll
    for (int i = 0; i < 2; i++) Sacc[ti][i] = (f32x4){0.f,0.f,0.f,0.f};
  for (int i = t; i < 64*136/2; i += 512) ((unsigned int*)S16T)[i] = 0;

  ushort4 krg[4];
  short8 Qnext[4], Qcur[4];
  short8 Wnext[4], Wcur[4];
  unsigned long long Unext[2], Ucur[2];
  float gl64;

  auto prefetch = [&](int c) {
    const int cb = (c*NVH + h) * 64;
    const __hip_bfloat16* qbase = qn + (size_t)(c*64 + 16*jt + fm)*KEY_DIM + sh*128 + fq*8;
    #pragma unroll
    for (int k4 = 0; k4 < 4; k4++)
      Qnext[k4] = *(const short8*)&qbase[k4*32];
    #pragma unroll
    for (int jj = 0; jj < 4; jj++)
      krg[jj] = *(const ushort4*)&kn[(size_t)(c*64 + kj + jj)*KEY_DIM + sh*128 + kd];
    #pragma unroll
    for (int k4 = 0; k4 < 4; k4++)
      Wnext[k4] = *(const short8*)&Wb[(size_t)(cb + 16*jt + fm)*128 + k4*32 + fq*8];
    #pragma unroll
    for (int i = 0; i < 2; i++) {
      const int tj = 2*nh + i;
      Unext[i] = *(const unsigned long long*)
          &UbT[(((size_t)c*NVH + h)*128 + vt*64 + 16*tj + fm)*64 + j0];
    }
    if (t < 64) gl64 = Gbuf[(size_t)cb + t];
  };

  auto stage = [&](int buf) {
    if (t < 64) Gs[t] = gl64;
    union { ushort4 v[4]; unsigned short u[16]; } kk;
    #pragma unroll
    for (int jj = 0; jj < 4; jj++) kk.v[jj] = krg[jj];
    #pragma unroll
    for (int dd = 0; dd < 4; dd++) {
      union { unsigned short u[4]; unsigned long long q; } p;
      #pragma unroll
      for (int jj = 0; jj < 4; jj++) p.u[jj] = kk.u[jj*4 + dd];
      *(unsigned long long*)&kT[buf][kd + dd][kj] = p.q;
    }
  };

  prefetch(0);
  #pragma unroll
  for (int k4 = 0; k4 < 4; k4++) { Qcur[k4] = Qnext[k4]; Wcur[k4] = Wnext[k4]; }
  #pragma unroll
  for (int i = 0; i < 2; i++) Ucur[i] = Unext[i];
  bar_lgkm();               // S16T zero-init visible
  stage(0);
  bar_lgkm();               // chunk-0 staging + Gs visible

  for (int c = 0; c < NCH; c++) {
    prefetch(c + 1 < NCH ? c + 1 : 0);

    f32x4 aX[2], aO[2];
    #pragma unroll
    for (int i = 0; i < 2; i++) {
      aX[i] = (f32x4){0.f,0.f,0.f,0.f};
      aO[i] = (f32x4){0.f,0.f,0.f,0.f};
    }
    __builtin_amdgcn_s_setprio(1);
    #pragma unroll
    for (int k4 = 0; k4 < 4; k4++) {
      #pragma unroll
      for (int i = 0; i < 2; i++) {
        const int tj = 2*nh + i;
        short8 b = *(const short8*)&S16T[16*tj + fm][k4*32 + fq*8];
        aX[i] = __builtin_amdgcn_mfma_f32_16x16x32_bf16(Wcur[k4], b, aX[i], 0, 0, 0);
        aO[i] = __builtin_amdgcn_mfma_f32_16x16x32_bf16(Qcur[k4], b, aO[i], 0, 0, 0);
      }
    }
    __builtin_amdgcn_s_setprio(0);
    const int cb = (c*NVH + h) * 64;
    const float gC = Gs[63];
    float er[4], os[4];
    #pragma unroll
    for (int r2 = 0; r2 < 4; r2++) {
      const float gj = Gs[j0 + r2];
      os[r2] = expf(gj);
      er[r2] = expf(gC - gj);
    }
    #pragma unroll
    for (int i = 0; i < 2; i++) {
      const int tj = 2*nh + i;
      const int n = 16*tj + fm;
      union { unsigned long long u; __hip_bfloat16 b[4]; } u4;
      u4.u = Ucur[i];
      union { __hip_bfloat16 b[4]; unsigned long long u; } pd;
      #pragma unroll
      for (int r2 = 0; r2 < 4; r2++) {
        const int j = j0 + r2;
        float d = __bfloat162float(u4.b[r2]) - aX[i][r2];
        Db[(size_t)(cb + j)*128 + vt*64 + n] = __float2bfloat16(d);
        pd.b[r2] = __float2bfloat16(d * er[r2]);
        obuf[((size_t)(c*64 + j)*NVH + h)*128 + vt*64 + n] = aO[i][r2] * os[r2];
      }
      *(unsigned long long*)&dT[n][j0] = pd.u;
    }
    const float lamC = expf(gC);
    #pragma unroll
    for (int ti = 0; ti < 2; ti++)
      #pragma unroll
      for (int i = 0; i < 2; i++)
        #pragma unroll
        for (int r2 = 0; r2 < 4; r2++) Sacc[ti][i][r2] *= lamC;
    bar_lgkm();
    __builtin_amdgcn_s_setprio(1);
    #pragma unroll
    for (int ti = 0; ti < 2; ti++) {
      const int m0 = 32*dt + 16*ti;
      #pragma unroll
      for (int kk0 = 0; kk0 < 64; kk0 += 32) {
        short8 aK = *(const short8*)&kT[c & 1][m0 + fm][kk0 + fq*8];
        #pragma unroll
        for (int i = 0; i < 2; i++) {
          const int tj = 2*nh + i;
          short8 bD = *(const short8*)&dT[16*tj + fm][kk0 + fq*8];
          Sacc[ti][i] = __builtin_amdgcn_mfma_f32_16x16x32_bf16(aK, bD, Sacc[ti][i], 0, 0, 0);
        }
      }
    }
    __builtin_amdgcn_s_setprio(0);
    #pragma unroll
    for (int ti = 0; ti < 2; ti++) {
      const int dk0 = 32*dt + 16*ti + fq*4;
      #pragma unroll
      for (int i = 0; i < 2; i++) {
        const int tj = 2*nh + i;
        const int n = 16*tj + fm;
        union { __hip_bfloat16 b[4]; unsigned long long u; } ps;
        #pragma unroll
        for (int r2 = 0; r2 < 4; r2++) ps.b[r2] = __float2bfloat16(Sacc[ti][i][r2]);
        *(unsigned long long*)&S16T[n][dk0] = ps.u;
      }
    }
    stage((c + 1) & 1);
    #pragma unroll
    for (int k4 = 0; k4 < 4; k4++) { Qcur[k4] = Qnext[k4]; Wcur[k4] = Wnext[k4]; }
    #pragma unroll
    for (int i = 0; i < 2; i++) Ucur[i] = Unext[i];
    bar_lgkm();
  }
}

// ---------------------------------------------------------------------------
// Phase C v3 (unchanged from R6): both GEMMs via MFMA
// ---------------------------------------------------------------------------
__global__ __launch_bounds__(256) void phaseC_kernel(
    const __hip_bfloat16* __restrict__ qn, const __hip_bfloat16* __restrict__ kn,
    const float* __restrict__ Gbuf, const __hip_bfloat16* __restrict__ Db,
    float* __restrict__ obuf) {
  const int h = blockIdx.x, c = blockIdx.y, sh = h >> 1;
  const int t = threadIdx.x, lane = t & 63, w = t >> 6;
  const int fm = lane & 15, fq = lane >> 4;
  __shared__ __hip_bfloat16 qch[64][136];   // [j][dk]
  __shared__ __hip_bfloat16 kch[64][136];   // [l][dk]
  __shared__ __hip_bfloat16 dchT[128][72];  // [n][l]
  __shared__ __hip_bfloat16 Pbf[64][72];    // [j][l]
  __shared__ float Gs[64];

  {
    const int r = t >> 2, c0 = (t & 3) * 32;
    const __hip_bfloat16* qrow = qn + (size_t)(c*64 + r)*KEY_DIM + sh*128 + c0;
    const __hip_bfloat16* krow = kn + (size_t)(c*64 + r)*KEY_DIM + sh*128 + c0;
    #pragma unroll
    for (int i = 0; i < 4; i++) {
      *(short8*)&qch[r][c0 + 8*i] = *(const short8*)&qrow[8*i];
      *(short8*)&kch[r][c0 + 8*i] = *(const short8*)&krow[8*i];
    }
    const __hip_bfloat16* drow = Db + ((size_t)c*NVH + h)*64*128 + (size_t)r*128 + c0;
    #pragma unroll
    for (int i = 0; i < 4; i++) {
      union { short8 s; unsigned short u[8]; } dv;
      dv.s = *(const short8*)&drow[8*i];
      #pragma unroll
      for (int e = 0; e < 8; e++)
        *(unsigned short*)&dchT[c0 + 8*i + e][r] = dv.u[e];
    }
  }
  if (t < 64) Gs[t] = Gbuf[((size_t)c*NVH + h)*64 + t];
  __syncthreads();

  {
    f32x4 pacc[4];
    #pragma unroll
    for (int lt = 0; lt < 4; lt++) pacc[lt] = (f32x4){0.f,0.f,0.f,0.f};
    #pragma unroll
    for (int k4 = 0; k4 < 4; k4++) {
      short8 aQ = *(const short8*)&qch[16*w + fm][k4*32 + fq*8];
      #pragma unroll
      for (int lt = 0; lt < 4; lt++) {
        short8 bK = *(const short8*)&kch[16*lt + fm][k4*32 + fq*8];
        pacc[lt] = __builtin_amdgcn_mfma_f32_16x16x32_bf16(aQ, bK, pacc[lt], 0, 0, 0);
      }
    }
    #pragma unroll
    for (int lt = 0; lt < 4; lt++)
      #pragma unroll
      for (int r2 = 0; r2 < 4; r2++) {
        const int j = 16*w + fq*4 + r2, l = 16*lt + fm;
        float v = (l <= j) ? expf(Gs[j] - Gs[l]) * pacc[lt][r2] : 0.f;
        Pbf[j][l] = __float2bfloat16(v);
      }
  }
  // no barrier: Pbf rows [16w,16w+16) are written and read by the same wave

  {
    f32x4 oacc[8];
    #pragma unroll
    for (int nt = 0; nt < 8; nt++) oacc[nt] = (f32x4){0.f,0.f,0.f,0.f};
    #pragma unroll
    for (int ks = 0; ks < 2; ks++) {
      short8 aP = *(const short8*)&Pbf[16*w + fm][ks*32 + fq*8];
      #pragma unroll
      for (int nt = 0; nt < 8; nt++) {
        short8 bD = *(const short8*)&dchT[16*nt + fm][ks*32 + fq*8];
        oacc[nt] = __builtin_amdgcn_mfma_f32_16x16x32_bf16(aP, bD, oacc[nt], 0, 0, 0);
      }
    }
    #pragma unroll
    for (int nt = 0; nt < 8; nt++)
      #pragma unroll
      for (int r2 = 0; r2 < 4; r2++) {
        const int j = 16*w + fq*4 + r2, n = 16*nt + fm;
        float* p = &obuf[((size_t)(c*64 + j)*NVH + h)*128 + n];
        *p += oacc[nt][r2];
      }
  }
}

// ---------------------------------------------------------------------------
// Gated RMSNorm -> bf16 (gate read from fused pre, cols 4096..6143)
// ---------------------------------------------------------------------------
__global__ __launch_bounds__(128) void norm_kernel(
    const float* __restrict__ o, const float* __restrict__ pre,
    const float* __restrict__ w_norm, __hip_bfloat16* __restrict__ og) {
  const int s = blockIdx.x, h = blockIdx.y, t = threadIdx.x;
  const size_t idx = (size_t)s * VAL_DIM + h * 128 + t;
  const size_t gidx = (size_t)s * NPROJ + 4096 + h * 128 + t;
  float gt = pre[gidx];
  float val = o[idx] * (gt / (1.f + expf(-gt)));
  float ss = val * val;
  #pragma unroll
  for (int off = 1; off < 64; off <<= 1) ss += __shfl_xor(ss, off, 64);
  __shared__ float red[2];
  if ((t & 63) == 0) red[t >> 6] = ss;
  __syncthreads();
  float ms = (red[0] + red[1]) * (1.f / 128.f);
  og[idx] = __float2bfloat16(val * (1.f / sqrtf(ms + 1e-6f)) * w_norm[t]);
}

// ---------------------------------------------------------------------------
extern "C" void kernel_launch(void* const* d_in, const int* in_sizes, int n_in,
                              void* d_out, int out_size, void* d_ws, size_t ws_size,
                              hipStream_t stream) {
  const float* x       = (const float*)d_in[0];
  const float* Wq      = (const float*)d_in[1];
  const float* Wk      = (const float*)d_in[2];
  const float* Wv      = (const float*)d_in[3];
  const float* Wa      = (const float*)d_in[4];
  const float* Wb_     = (const float*)d_in[5];
  const float* Wg      = (const float*)d_in[6];
  const float* Wo      = (const float*)d_in[7];
  const float* conv_q  = (const float*)d_in[8];
  const float* conv_k  = (const float*)d_in[9];
  const float* conv_v  = (const float*)d_in[10];
  const float* A_log   = (const float*)d_in[11];
  const float* dt_bias = (const float*)d_in[12];
  const float* w_norm  = (const float*)d_in[13];
  float* out = (float*)d_out;

  // ---- workspace layout (floats) -----------------------------------------
  // pre   [S][6144]                 @ 0          25,165,824
  // qn    bf16 S*1024               @ 25,165,824  2,097,152
  // kn    bf16 S*1024               @ 27,262,976  2,097,152
  // vcb   f32 S*2048 (later obuf)   @ 29,360,128  8,388,608
  // a_pre/b_pre/glb/beta/Gbuf       @ 37,748,736  5*65,536
  // arena: xb bf16 (4,194,304 fl) | wts_qkvg bf16 (6,291,456 fl) | wo bf16 (2,097,152 fl)
  //                                 @ 38,076,416 12,582,912
  //   after QKVG GEMM, [xb|wts_qkvg] is dead -> UbT @arena+0 (4,194,304 fl),
  //   Db @arena+4,194,304 (4,194,304 fl); ogb reuses Db after phaseC.
  // Wbb   bf16 S*NVH*128... (4,194,304 fl) @ 50,659,328
  // total 54,853,632 floats = 219.4 MB
  float* W = (float*)d_ws;
  float* pre   = W;
  __hip_bfloat16* qn = (__hip_bfloat16*)(W + 25165824);
  __hip_bfloat16* kn = (__hip_bfloat16*)(W + 27262976);
  float* vcb   = W + 29360128;
  float* a_pre = W + 37748736;
  float* b_pre = a_pre + 65536;
  float* glb   = b_pre + 65536;
  float* beta  = glb + 65536;
  float* Gbuf  = beta + 65536;
  __hip_bfloat16* xb  = (__hip_bfloat16*)(W + 38076416);
  __hip_bfloat16* wts = xb + 8388608;          // 12,582,912 elems (q|k|v|g)
  __hip_bfloat16* wo  = wts + 12582912;        // 4,194,304 elems
  __hip_bfloat16* Wbb = (__hip_bfloat16*)(W + 50659328);
  __hip_bfloat16* UbT = (__hip_bfloat16*)(W + 38076416);             // over xb
  __hip_bfloat16* Db  = (__hip_bfloat16*)(W + 38076416 + 4194304);   // over wts
  __hip_bfloat16* ogb = Db;                    // after phaseC done with Db
  float* obuf = vcb;                            // after phaseA done with vcb

  // 1. casts
  cast_f2b<<<(S_LEN*HID)/1024, 256, 0, stream>>>(x, xb, S_LEN*HID);
  cast5<<<16777216/1024, 256, 0, stream>>>(Wq, Wk, Wv, Wg, Wo, wts);
  // 2. tiny projections (Wa, Wb in one launch)
  gemm_bt2<<<dim3(2, S_LEN/64), 256, 0, stream>>>(x, Wa, Wb_, a_pre, b_pre, HID);
  // 3. fused q|k|v|gate projection GEMM: [S][6144] = xb @ wts^T
  gemm_bf16_bt<<<dim3(NPROJ/128, S_LEN/128), 256, 0, stream>>>(xb, wts, pre, S_LEN, NPROJ, HID);
  // 4. convs + gating scalars
  conv_qk_kernel<<<dim3(S_LEN, 16), 128, 0, stream>>>(pre, conv_q, conv_k, qn, kn);
  conv_v_kernel<<<(S_LEN*VAL_DIM)/256, 256, 0, stream>>>(pre, conv_v, vcb);
  gb_kernel<<<(S_LEN*NVH)/256, 256, 0, stream>>>(a_pre, b_pre, A_log, dt_bias, glb, beta);
  // 5. chunked delta-rule scan
  phaseA_kernel<<<dim3(NVH, NCH), 256, 0, stream>>>(kn, vcb, glb, beta, Wbb, UbT, Gbuf);
  phaseB_kernel<<<2*NVH, 512, 0, stream>>>(qn, kn, Wbb, UbT, Gbuf, Db, obuf);
  phaseC_kernel<<<dim3(NVH, NCH), 256, 0, stream>>>(qn, kn, Gbuf, Db, obuf);
  // 6. gated RMSNorm + output projection
  norm_kernel<<<dim3(S_LEN, NVH), 128, 0, stream>>>(obuf, pre, w_norm, ogb);
  gemm_bf16_bt<<<dim3(HID/128, S_LEN/128), 256, 0, stream>>>(ogb, wo, out, S_LEN, HID, VAL_DIM);
}

// Round 8
// 984.101 us; speedup vs baseline: 1.4841x; 1.0164x over previous
//
#include <hip/hip_runtime.h>
#include <hip/hip_bf16.h>
#include <math.h>

#define S_LEN 4096
#define HID   2048
#define NH    8
#define NVH   16
#define DK    128
#define DV    128
#define KEY_DIM  (NH*DK)    // 1024
#define VAL_DIM  (NVH*DV)   // 2048
#define NPROJ 6144          // fused q|k|v|gate projection width
#define SCALE_Q  0.08838834764831845f  // 128^-0.5
#define CCH 64              // chunk length
#define NCH (S_LEN/CCH)     // 64 chunks

typedef __attribute__((ext_vector_type(8))) short short8;   // 8 bf16
typedef __attribute__((ext_vector_type(4))) float f32x4;

// ---------------------------------------------------------------------------
// float -> bf16 cast (single src)
// ---------------------------------------------------------------------------
__global__ __launch_bounds__(256) void cast_f2b(
    const float* __restrict__ in, __hip_bfloat16* __restrict__ out, int n) {
  int i = (blockIdx.x * 256 + threadIdx.x) * 4;
  if (i >= n) return;
  float4 v = *(const float4*)&in[i];
  union { __hip_bfloat16 b[4]; short4 s; } u;
  u.b[0] = __float2bfloat16(v.x); u.b[1] = __float2bfloat16(v.y);
  u.b[2] = __float2bfloat16(v.z); u.b[3] = __float2bfloat16(v.w);
  *(short4*)&out[i] = u.s;
}

// ---------------------------------------------------------------------------
// 5-weight cast into one contiguous bf16 arena: [Wq|Wk|Wv|Wg|Wo]
// ---------------------------------------------------------------------------
__global__ __launch_bounds__(256) void cast5(
    const float* __restrict__ w0, const float* __restrict__ w1,
    const float* __restrict__ w2, const float* __restrict__ w3,
    const float* __restrict__ w4, __hip_bfloat16* __restrict__ dst) {
  int i = (blockIdx.x * 256 + threadIdx.x) * 4;
  const float* src; int off;
  if      (i <  2097152) { src = w0; off = 0; }
  else if (i <  4194304) { src = w1; off = 2097152; }
  else if (i <  8388608) { src = w2; off = 4194304; }
  else if (i < 12582912) { src = w3; off = 8388608; }
  else                   { src = w4; off = 12582912; }
  float4 v = *(const float4*)&src[i - off];
  union { __hip_bfloat16 b[4]; short4 s; } u;
  u.b[0] = __float2bfloat16(v.x); u.b[1] = __float2bfloat16(v.y);
  u.b[2] = __float2bfloat16(v.z); u.b[3] = __float2bfloat16(v.w);
  *(short4*)&dst[i] = u.s;
}

// ---------------------------------------------------------------------------
// bf16 MFMA GEMM: C[M,N](fp32) = A[M,K] @ B[N,K]^T  (m97 structure)
// ---------------------------------------------------------------------------
__device__ __forceinline__ void lds_load16(const __hip_bfloat16* g,
                                           __hip_bfloat16* l) {
  __builtin_amdgcn_global_load_lds(
      (const __attribute__((address_space(1))) unsigned int*)g,
      (__attribute__((address_space(3))) unsigned int*)l, 16, 0, 0);
}

__global__ __launch_bounds__(256) void gemm_bf16_bt(
    const __hip_bfloat16* __restrict__ A, const __hip_bfloat16* __restrict__ B,
    float* __restrict__ C, int M, int N, int K) {
  __shared__ __hip_bfloat16 sA[128 * 32];
  __shared__ __hip_bfloat16 sB[128 * 32];
  const int t = threadIdx.x;
  const int wave = t >> 6, lane = t & 63;
  const int bm = blockIdx.y, bn = blockIdx.x;
  const int wm = (wave & 1) * 64, wn = (wave >> 1) * 64;

  f32x4 zero = {0.f, 0.f, 0.f, 0.f};
  f32x4 acc[4][4];
  #pragma unroll
  for (int i = 0; i < 4; i++)
    #pragma unroll
    for (int j = 0; j < 4; j++) acc[i][j] = zero;

  const int r0 = t >> 2,        c0 = (t & 3) * 8;
  const int r1 = (256 + t) >> 2, c1 = ((256 + t) & 3) * 8;
  const __hip_bfloat16* gA0 = A + (size_t)(bm * 128 + r0) * K + c0;
  const __hip_bfloat16* gA1 = A + (size_t)(bm * 128 + r1) * K + c1;
  const __hip_bfloat16* gB0 = B + (size_t)(bn * 128 + r0) * K + c0;
  const __hip_bfloat16* gB1 = B + (size_t)(bn * 128 + r1) * K + c1;
  __hip_bfloat16* lA0 = sA + (size_t)(wave * 64) * 8;
  __hip_bfloat16* lA1 = sA + (size_t)(256 + wave * 64) * 8;
  __hip_bfloat16* lB0 = sB + (size_t)(wave * 64) * 8;
  __hip_bfloat16* lB1 = sB + (size_t)(256 + wave * 64) * 8;

  const int fm = lane & 15, fk = (lane >> 4) * 8;

  for (int k0 = 0; k0 < K; k0 += 32) {
    lds_load16(gA0, lA0); lds_load16(gA1, lA1);
    lds_load16(gB0, lB0); lds_load16(gB1, lB1);
    gA0 += 32; gA1 += 32; gB0 += 32; gB1 += 32;
    __syncthreads();
    short8 a[4], b[4];
    #pragma unroll
    for (int i = 0; i < 4; i++)
      a[i] = *(const short8*)&sA[(size_t)(wm + i * 16 + fm) * 32 + fk];
    #pragma unroll
    for (int j = 0; j < 4; j++)
      b[j] = *(const short8*)&sB[(size_t)(wn + j * 16 + fm) * 32 + fk];
    #pragma unroll
    for (int i = 0; i < 4; i++)
      #pragma unroll
      for (int j = 0; j < 4; j++)
        acc[i][j] = __builtin_amdgcn_mfma_f32_16x16x32_bf16(a[i], b[j], acc[i][j], 0, 0, 0);
    __syncthreads();
  }
  #pragma unroll
  for (int i = 0; i < 4; i++) {
    #pragma unroll
    for (int j = 0; j < 4; j++) {
      int col = bn * 128 + wn + j * 16 + (lane & 15);
      int rw0 = bm * 128 + wm + i * 16 + (lane >> 4) * 4;
      #pragma unroll
      for (int r = 0; r < 4; r++)
        C[(size_t)(rw0 + r) * N + col] = acc[i][j][r];
    }
  }
}

// ---------------------------------------------------------------------------
// fp32 GEMM for the tiny N=16 projections: one launch does BOTH Wa and Wb
// ---------------------------------------------------------------------------
__global__ __launch_bounds__(256) void gemm_bt2(
    const float* __restrict__ A, const float* __restrict__ Ba,
    const float* __restrict__ Bb, float* __restrict__ Ca,
    float* __restrict__ Cb, int K) {
  const float* B = blockIdx.x == 0 ? Ba : Bb;
  float* C       = blockIdx.x == 0 ? Ca : Cb;
  const int N = NVH;  // 16
  __shared__ float As[16][68];
  __shared__ float Bs[16][68];
  const int bm = blockIdx.y;
  const int t = threadIdx.x;
  const int tx = t & 15, ty = t >> 4;
  const int lrow = t >> 2;
  const int lk0  = (t & 3) * 4;
  const int arow = bm * 64 + lrow;
  const bool bvalid = lrow < N;

  float acc[4][4];
  #pragma unroll
  for (int i = 0; i < 4; i++)
    #pragma unroll
    for (int j = 0; j < 4; j++) acc[i][j] = 0.f;

  for (int k0 = 0; k0 < K; k0 += 16) {
    float4 av = *(const float4*)&A[(size_t)arow * K + k0 + lk0];
    float4 bv = bvalid ? *(const float4*)&B[(size_t)lrow * K + k0 + lk0]
                       : make_float4(0.f, 0.f, 0.f, 0.f);
    As[lk0+0][lrow] = av.x; As[lk0+1][lrow] = av.y;
    As[lk0+2][lrow] = av.z; As[lk0+3][lrow] = av.w;
    Bs[lk0+0][lrow] = bv.x; Bs[lk0+1][lrow] = bv.y;
    Bs[lk0+2][lrow] = bv.z; Bs[lk0+3][lrow] = bv.w;
    __syncthreads();
    #pragma unroll
    for (int kk = 0; kk < 16; kk++) {
      float4 a = *(const float4*)&As[kk][ty * 4];
      float4 b = *(const float4*)&Bs[kk][tx * 4];
      float ar[4] = {a.x, a.y, a.z, a.w};
      float br[4] = {b.x, b.y, b.z, b.w};
      #pragma unroll
      for (int i = 0; i < 4; i++)
        #pragma unroll
        for (int j = 0; j < 4; j++) acc[i][j] += ar[i] * br[j];
    }
    __syncthreads();
  }
  #pragma unroll
  for (int i = 0; i < 4; i++) {
    int r = bm * 64 + ty * 4 + i;
    #pragma unroll
    for (int j = 0; j < 4; j++) {
      int c = tx * 4 + j;
      if (c < N) C[(size_t)r * N + c] = acc[i][j];
    }
  }
}

// ---------------------------------------------------------------------------
// conv + SiLU + l2norm for q AND k in one launch
// ---------------------------------------------------------------------------
__global__ __launch_bounds__(128) void conv_qk_kernel(
    const float* __restrict__ pre, const float* __restrict__ cwq,
    const float* __restrict__ cwk, __hip_bfloat16* __restrict__ qn,
    __hip_bfloat16* __restrict__ kn) {
  const int s = blockIdx.x, y = blockIdx.y, t = threadIdx.x;
  const bool isq = y < 8;
  const int h = isq ? y : y - 8;
  const int ch = h * 128 + t;
  const float* cw = isq ? cwq : cwk;
  const int col = (isq ? 0 : 1024) + ch;
  const float4 w = *(const float4*)&cw[ch * 4];
  const size_t base = (size_t)s * NPROJ + col;
  float v0 = pre[base] * w.w;
  if (s >= 1) v0 += pre[base - NPROJ]     * w.z;
  if (s >= 2) v0 += pre[base - 2*NPROJ]   * w.y;
  if (s >= 3) v0 += pre[base - 3*NPROJ]   * w.x;
  float v = v0 / (1.f + expf(-v0));
  float ss = v * v;
  #pragma unroll
  for (int off = 1; off < 64; off <<= 1) ss += __shfl_xor(ss, off, 64);
  __shared__ float red[2];
  if ((t & 63) == 0) red[t >> 6] = ss;
  __syncthreads();
  const float scale = isq ? SCALE_Q : 1.f;
  float inv = scale / sqrtf(red[0] + red[1] + 1e-6f);
  __hip_bfloat16* out = isq ? qn : kn;
  out[((size_t)s * NH + h) * 128 + t] = __float2bfloat16(v * inv);
}

// ---------------------------------------------------------------------------
// conv + SiLU for v (reads fused pre, cols 2048..4095)
// ---------------------------------------------------------------------------
__global__ __launch_bounds__(256) void conv_v_kernel(
    const float* __restrict__ pre, const float* __restrict__ cw,
    float* __restrict__ out) {
  const int id = blockIdx.x * 256 + threadIdx.x;
  const int s = id >> 11, c = id & 2047;
  const float4 w = *(const float4*)&cw[c * 4];
  const size_t base = (size_t)s * NPROJ + 2048 + c;
  float y = pre[base] * w.w;
  if (s >= 1) y += pre[base - NPROJ]     * w.z;
  if (s >= 2) y += pre[base - 2*NPROJ]   * w.y;
  if (s >= 3) y += pre[base - 3*NPROJ]   * w.x;
  out[id] = y / (1.f + expf(-y));
}

// ---------------------------------------------------------------------------
// gl = -exp(A_log)*softplus(a+dt_bias), beta = sigmoid(b)
// ---------------------------------------------------------------------------
__global__ __launch_bounds__(256) void gb_kernel(
    const float* __restrict__ a_pre, const float* __restrict__ b_pre,
    const float* __restrict__ A_log, const float* __restrict__ dt_bias,
    float* __restrict__ gl, float* __restrict__ bv) {
  const int id = blockIdx.x * 256 + threadIdx.x;
  const int h = id & 15;
  float av = a_pre[id] + dt_bias[h];
  float sp = av > 20.f ? av : log1pf(expf(av));
  gl[id] = -expf(A_log[h]) * sp;
  bv[id] = 1.f / (1.f + expf(-b_pre[id]));
}

// ---------------------------------------------------------------------------
// Phase A v5: the affine-recurrence precompute. Per (h,c) computes and writes:
//   amNeg = -K^T diag(er) W          [128][128] bf16   (er_l = e^{gC-G_l})
//   Bm    =  K^T diag(er) U          [128][128] bf16
//   q2    =  e^{Gj} q_j - (P W)_j    [64][128]  bf16   (P_jl = e^{Gj-Gl} q_j.k_l, l<=j)
//   olocal=  P U  -> written into obuf (same cells as the v it consumed)
//   lam   =  e^{gC}
// so phaseB's serial loop is just S <- lam*S + Bm + amNeg*S and o = q2*S + olocal.
// phaseC is eliminated. Manual LDS layout (153KB) with post-solve overlays.
// ---------------------------------------------------------------------------
__global__ __launch_bounds__(256) void phaseA_kernel(
    const __hip_bfloat16* __restrict__ qn, const __hip_bfloat16* __restrict__ kn,
    float* __restrict__ vc,   // v in; olocal out (same region per block)
    const float* __restrict__ gl, const float* __restrict__ bvv,
    __hip_bfloat16* __restrict__ amNeg, __hip_bfloat16* __restrict__ Bmo,
    __hip_bfloat16* __restrict__ q2, float* __restrict__ lam) {
  const int h = blockIdx.x, c = blockIdx.y, sh = h >> 1;
  const int t = threadIdx.x, lane = t & 63, w = t >> 6;   // 4 waves
  const int fm = lane & 15, fq = lane >> 4;

  __shared__ char smem[153088];
  __hip_bfloat16* kch = (__hip_bfloat16*)(smem);           // [64][136]
  __hip_bfloat16* kTe = (__hip_bfloat16*)(smem + 17408);   // [128][72] er-folded K^T
  float* vch = (float*)(smem + 35840);                     // [64][132]
  float* mm  = (float*)(smem + 69632);                     // [64][65]
  float* sol = (float*)(smem + 86272);                     // [64][257]
  float* Gs  = (float*)(smem + 152064);
  float* bet = Gs + 64; float* lamB = bet + 64; float* er = lamB + 64;
  // post-solve overlays:
  __hip_bfloat16* WT = (__hip_bfloat16*)(smem + 35840);    // [128][72] over vch
  __hip_bfloat16* UT = (__hip_bfloat16*)(smem + 54272);    // [128][72] over vch/mm
  __hip_bfloat16* Pl = (__hip_bfloat16*)(smem + 86272);    // [64][72] over sol

  // 1. stage k (bf16) + v (f32)
  {
    const int r = t >> 2, c0 = (t & 3) * 32;
    const __hip_bfloat16* krow = kn + (size_t)(c*64 + r)*KEY_DIM + sh*128 + c0;
    const float* vrow = vc + (size_t)(c*64 + r)*VAL_DIM + h*128 + c0;
    #pragma unroll
    for (int i = 0; i < 4; i++)
      *(short8*)&kch[r*136 + c0 + 8*i] = *(const short8*)&krow[8*i];
    #pragma unroll
    for (int i = 0; i < 8; i++)
      *(float4*)&vch[r*132 + c0 + 4*i] = *(const float4*)&vrow[4*i];
  }
  if (t < 64) {
    float g = gl[(size_t)(c*64 + t)*NVH + h];
    #pragma unroll
    for (int off = 1; off < 64; off <<= 1) {
      float p = __shfl_up(g, off, 64);
      if (t >= off) g += p;
    }
    Gs[t] = g;
    float gC = __shfl(g, 63, 64);
    er[t] = expf(gC - g);
    float b = bvv[(size_t)(c*64 + t)*NVH + h];
    bet[t] = b;
    lamB[t] = b * expf(g);
    if (t == 0) lam[c*NVH + h] = expf(gC);
  }
  __syncthreads();

  // 2. mm[j][l] via MFMA + kTe transpose-write (er-folded)
  {
    f32x4 pacc[4];
    #pragma unroll
    for (int lt = 0; lt < 4; lt++) pacc[lt] = (f32x4){0.f,0.f,0.f,0.f};
    #pragma unroll
    for (int k4 = 0; k4 < 4; k4++) {
      short8 aK = *(const short8*)&kch[(16*w + fm)*136 + k4*32 + fq*8];
      #pragma unroll
      for (int lt = 0; lt < 4; lt++) {
        short8 bK = *(const short8*)&kch[(16*lt + fm)*136 + k4*32 + fq*8];
        pacc[lt] = __builtin_amdgcn_mfma_f32_16x16x32_bf16(aK, bK, pacc[lt], 0, 0, 0);
      }
    }
    #pragma unroll
    for (int lt = 0; lt < 4; lt++)
      #pragma unroll
      for (int r2 = 0; r2 < 4; r2++) {
        const int j = 16*w + fq*4 + r2, l = 16*lt + fm;
        mm[j*65 + l] = (l < j) ? bet[j] * expf(Gs[j] - Gs[l]) * pacc[lt][r2] : 0.f;
      }
  }
  {
    const int dk = t >> 1, jh = (t & 1) * 32;
    for (int j = jh; j < jh + 32; j += 2) {
      union { __hip_bfloat16 b[2]; unsigned u; } p;
      p.b[0] = __float2bfloat16(er[j]   * __bfloat162float(kch[j*136 + dk]));
      p.b[1] = __float2bfloat16(er[j+1] * __bfloat162float(kch[(j+1)*136 + dk]));
      *(unsigned*)&kTe[dk*72 + j] = p.u;
    }
  }
  __syncthreads();

  // 3. triangular solve (W in sol cols 0..127, U in cols 128..255)
  {
    const bool isW = t < 128;
    const int col = t & 127;
    for (int j = 0; j < 64; j++) {
      float s0 = isW ? lamB[j] * __bfloat162float(kch[j*136 + col])
                     : bet[j] * vch[j*132 + col];
      float s1 = 0.f;
      int l = 0;
      for (; l + 1 < j; l += 2) {
        s0 = fmaf(-mm[j*65 + l],     sol[l*257 + t],     s0);
        s1 = fmaf(-mm[j*65 + l + 1], sol[(l+1)*257 + t], s1);
      }
      if (l < j) s0 = fmaf(-mm[j*65 + l], sol[l*257 + t], s0);
      sol[j*257 + t] = s0 + s1;
    }
  }
  __syncthreads();

  // 4. P-MFMA (held in regs) + WT/UT transpose writes (over vch/mm)
  f32x4 pP[4];
  #pragma unroll
  for (int lt = 0; lt < 4; lt++) pP[lt] = (f32x4){0.f,0.f,0.f,0.f};
  {
    short8 aQ[4];
    #pragma unroll
    for (int k4 = 0; k4 < 4; k4++)
      aQ[k4] = *(const short8*)&qn[((size_t)(c*64 + 16*w + fm)*NH + sh)*128 + k4*32 + fq*8];
    #pragma unroll
    for (int k4 = 0; k4 < 4; k4++)
      #pragma unroll
      for (int lt = 0; lt < 4; lt++) {
        short8 bK = *(const short8*)&kch[(16*lt + fm)*136 + k4*32 + fq*8];
        pP[lt] = __builtin_amdgcn_mfma_f32_16x16x32_bf16(aQ[k4], bK, pP[lt], 0, 0, 0);
      }
  }
  {
    const int colv = t & 127;
    const int base = (t < 128) ? 0 : 128;
    __hip_bfloat16* Tdst = (t < 128) ? WT : UT;
    for (int j = 0; j < 64; j += 2) {
      union { __hip_bfloat16 b[2]; unsigned u; } p;
      p.b[0] = __float2bfloat16(sol[j*257 + base + colv]);
      p.b[1] = __float2bfloat16(sol[(j+1)*257 + base + colv]);
      *(unsigned*)&Tdst[colv*72 + j] = p.u;
    }
  }
  __syncthreads();

  // 5. write P (over sol space)
  #pragma unroll
  for (int lt = 0; lt < 4; lt++)
    #pragma unroll
    for (int r2 = 0; r2 < 4; r2++) {
      const int j = 16*w + fq*4 + r2, l = 16*lt + fm;
      float v = (l <= j) ? expf(Gs[j] - Gs[l]) * pP[lt][r2] : 0.f;
      Pl[j*72 + l] = __float2bfloat16(v);
    }
  __syncthreads();

  // 6. products: amNeg/Bm (kTe x WT/UT), q2/olocal (P x WT/UT)
  const size_t gb = ((size_t)c*NVH + h) * 128;
  #pragma unroll
  for (int ti = 0; ti < 2; ti++) {
    const int m0 = 32*w + 16*ti;
    short8 aK[2];
    #pragma unroll
    for (int ks = 0; ks < 2; ks++)
      aK[ks] = *(const short8*)&kTe[(m0 + fm)*72 + ks*32 + fq*8];
    #pragma unroll
    for (int nt = 0; nt < 8; nt++) {
      f32x4 aA = (f32x4){0.f,0.f,0.f,0.f}, aB = (f32x4){0.f,0.f,0.f,0.f};
      #pragma unroll
      for (int ks = 0; ks < 2; ks++) {
        short8 bW = *(const short8*)&WT[(16*nt + fm)*72 + ks*32 + fq*8];
        short8 bU = *(const short8*)&UT[(16*nt + fm)*72 + ks*32 + fq*8];
        aA = __builtin_amdgcn_mfma_f32_16x16x32_bf16(aK[ks], bW, aA, 0, 0, 0);
        aB = __builtin_amdgcn_mfma_f32_16x16x32_bf16(aK[ks], bU, aB, 0, 0, 0);
      }
      #pragma unroll
      for (int r2 = 0; r2 < 4; r2++) {
        const int row = m0 + fq*4 + r2, col = 16*nt + fm;
        const size_t idx = (gb + row)*128 + col;
        amNeg[idx] = __float2bfloat16(-aA[r2]);
        Bmo[idx]   = __float2bfloat16(aB[r2]);
      }
    }
  }
  {
    float eg[4];
    #pragma unroll
    for (int r2 = 0; r2 < 4; r2++) eg[r2] = expf(Gs[16*w + fq*4 + r2]);
    short8 aP[2];
    #pragma unroll
    for (int ks = 0; ks < 2; ks++)
      aP[ks] = *(const short8*)&Pl[(16*w + fm)*72 + ks*32 + fq*8];
    #pragma unroll
    for (int nt = 0; nt < 8; nt++) {
      f32x4 aR = (f32x4){0.f,0.f,0.f,0.f}, aO = (f32x4){0.f,0.f,0.f,0.f};
      #pragma unroll
      for (int ks = 0; ks < 2; ks++) {
        short8 bW = *(const short8*)&WT[(16*nt + fm)*72 + ks*32 + fq*8];
        short8 bU = *(const short8*)&UT[(16*nt + fm)*72 + ks*32 + fq*8];
        aR = __builtin_amdgcn_mfma_f32_16x16x32_bf16(aP[ks], bW, aR, 0, 0, 0);
        aO = __builtin_amdgcn_mfma_f32_16x16x32_bf16(aP[ks], bU, aO, 0, 0, 0);
      }
      #pragma unroll
      for (int r2 = 0; r2 < 4; r2++) {
        const int j = 16*w + fq*4 + r2, dk = 16*nt + fm;
        float qv = __bfloat162float(qn[((size_t)(c*64 + j)*NH + sh)*128 + dk]);
        q2[(((size_t)c*NVH + h)*64 + j)*128 + dk] = __float2bfloat16(eg[r2]*qv - aR[r2]);
        vc[((size_t)(c*64 + j)*NVH + h)*128 + dk] = aO[r2];   // olocal -> obuf
      }
    }
  }
}

// ---------------------------------------------------------------------------
// Phase B v10: lean affine recurrence. Per chunk per wave: 8 ds_read_b128 +
// 24 MFMA + ~80 VALU. No exp, no Delta, no Db. 2 lgkm barriers/chunk.
// S <- lam*S(f32 regs) + Bm + amNeg . S_mirror ; obuf += q2 . S_mirror.
// ---------------------------------------------------------------------------
__device__ __forceinline__ void bar_lgkm() {
  asm volatile("s_waitcnt lgkmcnt(0)" ::: "memory");
  __builtin_amdgcn_s_barrier();
  asm volatile("" ::: "memory");
}

__global__ __launch_bounds__(512, 2) void phaseB_kernel(
    const __hip_bfloat16* __restrict__ q2, const __hip_bfloat16* __restrict__ amNeg,
    const __hip_bfloat16* __restrict__ Bmo, const float* __restrict__ lam,
    float* __restrict__ obuf) {
  const int bid = blockIdx.x;
  const int h = (bid & 7) | ((bid >> 4) << 3);   // (h,vt) pair on same XCD
  const int vt = (bid >> 3) & 1;
  const int t = threadIdx.x, lane = t & 63, w = t >> 6;   // 8 waves
  const int fm = lane & 15, fq = lane >> 4;
  const int jt = w >> 1, nh = w & 1, dt = w >> 1;

  __shared__ __hip_bfloat16 S16T[64][136];   // S mirror [n_loc][dk]
  for (int i = t; i < 64*136/2; i += 512) ((unsigned*)S16T)[i] = 0;

  f32x4 Sacc[2][2];
  #pragma unroll
  for (int ti = 0; ti < 2; ti++)
    #pragma unroll
    for (int i = 0; i < 2; i++) Sacc[ti][i] = (f32x4){0.f,0.f,0.f,0.f};

  short8 Qn[4], Qc[4];
  short8 An[2][4], Ac[2][4];
  __hip_bfloat16 Bn[2][2][4], Bc[2][2][4];
  float On[2][4], Oc[2][4];
  float lamn, lamc;

  auto prefetch = [&](int c) {
    const size_t hb = (size_t)c*NVH + h;
    #pragma unroll
    for (int k4 = 0; k4 < 4; k4++)
      Qn[k4] = *(const short8*)&q2[(hb*64 + 16*jt + fm)*128 + k4*32 + fq*8];
    #pragma unroll
    for (int ti = 0; ti < 2; ti++)
      #pragma unroll
      for (int k4 = 0; k4 < 4; k4++)
        An[ti][k4] = *(const short8*)&amNeg[(hb*128 + 32*dt + 16*ti + fm)*128 + k4*32 + fq*8];
    #pragma unroll
    for (int ti = 0; ti < 2; ti++)
      #pragma unroll
      for (int i = 0; i < 2; i++)
        #pragma unroll
        for (int r2 = 0; r2 < 4; r2++)
          Bn[ti][i][r2] = Bmo[(hb*128 + 32*dt + 16*ti + fq*4 + r2)*128 + vt*64 + 16*(2*nh+i) + fm];
    #pragma unroll
    for (int i = 0; i < 2; i++)
      #pragma unroll
      for (int r2 = 0; r2 < 4; r2++)
        On[i][r2] = obuf[((size_t)(c*64 + 16*jt + fq*4 + r2)*NVH + h)*128 + vt*64 + 16*(2*nh+i) + fm];
    lamn = lam[c*NVH + h];
  };

  auto pull = [&]() {
    #pragma unroll
    for (int k4 = 0; k4 < 4; k4++) Qc[k4] = Qn[k4];
    #pragma unroll
    for (int ti = 0; ti < 2; ti++)
      #pragma unroll
      for (int k4 = 0; k4 < 4; k4++) Ac[ti][k4] = An[ti][k4];
    #pragma unroll
    for (int ti = 0; ti < 2; ti++)
      #pragma unroll
      for (int i = 0; i < 2; i++)
        #pragma unroll
        for (int r2 = 0; r2 < 4; r2++) Bc[ti][i][r2] = Bn[ti][i][r2];
    #pragma unroll
    for (int i = 0; i < 2; i++)
      #pragma unroll
      for (int r2 = 0; r2 < 4; r2++) Oc[i][r2] = On[i][r2];
    lamc = lamn;
  };

  prefetch(0);
  pull();
  bar_lgkm();     // S16T zero-init visible

  for (int c = 0; c < NCH; c++) {
    prefetch(c + 1 < NCH ? c + 1 : 0);

    // shared B-operand fragments (used by both O and S phases)
    short8 sB[2][4];
    #pragma unroll
    for (int i = 0; i < 2; i++)
      #pragma unroll
      for (int k4 = 0; k4 < 4; k4++)
        sB[i][k4] = *(const short8*)&S16T[16*(2*nh+i) + fm][k4*32 + fq*8];

    __builtin_amdgcn_s_setprio(1);
    // O phase: o += q2 . S
    f32x4 aO[2];
    #pragma unroll
    for (int i = 0; i < 2; i++) aO[i] = (f32x4){0.f,0.f,0.f,0.f};
    #pragma unroll
    for (int k4 = 0; k4 < 4; k4++)
      #pragma unroll
      for (int i = 0; i < 2; i++)
        aO[i] = __builtin_amdgcn_mfma_f32_16x16x32_bf16(Qc[k4], sB[i][k4], aO[i], 0, 0, 0);
    // S phase: acc = lam*S + Bm + (-Am) . S_mirror
    f32x4 acc[2][2];
    #pragma unroll
    for (int ti = 0; ti < 2; ti++)
      #pragma unroll
      for (int i = 0; i < 2; i++)
        #pragma unroll
        for (int r2 = 0; r2 < 4; r2++)
          acc[ti][i][r2] = lamc * Sacc[ti][i][r2] + __bfloat162float(Bc[ti][i][r2]);
    #pragma unroll
    for (int k4 = 0; k4 < 4; k4++)
      #pragma unroll
      for (int ti = 0; ti < 2; ti++)
        #pragma unroll
        for (int i = 0; i < 2; i++)
          acc[ti][i] = __builtin_amdgcn_mfma_f32_16x16x32_bf16(Ac[ti][k4], sB[i][k4], acc[ti][i], 0, 0, 0);
    __builtin_amdgcn_s_setprio(0);

    // epilogue: obuf = olocal + o_inter
    #pragma unroll
    for (int i = 0; i < 2; i++)
      #pragma unroll
      for (int r2 = 0; r2 < 4; r2++)
        obuf[((size_t)(c*64 + 16*jt + fq*4 + r2)*NVH + h)*128 + vt*64 + 16*(2*nh+i) + fm]
            = Oc[i][r2] + aO[i][r2];
    #pragma unroll
    for (int ti = 0; ti < 2; ti++)
      #pragma unroll
      for (int i = 0; i < 2; i++) Sacc[ti][i] = acc[ti][i];

    bar_lgkm();   // A: all S16T reads complete
    // mirror refresh
    #pragma unroll
    for (int ti = 0; ti < 2; ti++) {
      const int dk0 = 32*dt + 16*ti + fq*4;
      #pragma unroll
      for (int i = 0; i < 2; i++) {
        union { __hip_bfloat16 b[4]; unsigned long long u; } ps;
        #pragma unroll
        for (int r2 = 0; r2 < 4; r2++) ps.b[r2] = __float2bfloat16(Sacc[ti][i][r2]);
        *(unsigned long long*)&S16T[16*(2*nh+i) + fm][dk0] = ps.u;
      }
    }
    pull();
    bar_lgkm();   // B: mirror visible for next chunk
  }
}

// ---------------------------------------------------------------------------
// Gated RMSNorm -> bf16 (gate from fused pre cols 4096..6143)
// ---------------------------------------------------------------------------
__global__ __launch_bounds__(128) void norm_kernel(
    const float* __restrict__ o, const float* __restrict__ pre,
    const float* __restrict__ w_norm, __hip_bfloat16* __restrict__ og) {
  const int s = blockIdx.x, h = blockIdx.y, t = threadIdx.x;
  const size_t idx = (size_t)s * VAL_DIM + h * 128 + t;
  const size_t gidx = (size_t)s * NPROJ + 4096 + h * 128 + t;
  float gt = pre[gidx];
  float val = o[idx] * (gt / (1.f + expf(-gt)));
  float ss = val * val;
  #pragma unroll
  for (int off = 1; off < 64; off <<= 1) ss += __shfl_xor(ss, off, 64);
  __shared__ float red[2];
  if ((t & 63) == 0) red[t >> 6] = ss;
  __syncthreads();
  float ms = (red[0] + red[1]) * (1.f / 128.f);
  og[idx] = __float2bfloat16(val * (1.f / sqrtf(ms + 1e-6f)) * w_norm[t]);
}

// ---------------------------------------------------------------------------
extern "C" void kernel_launch(void* const* d_in, const int* in_sizes, int n_in,
                              void* d_out, int out_size, void* d_ws, size_t ws_size,
                              hipStream_t stream) {
  const float* x       = (const float*)d_in[0];
  const float* Wq      = (const float*)d_in[1];
  const float* Wk      = (const float*)d_in[2];
  const float* Wv      = (const float*)d_in[3];
  const float* Wa      = (const float*)d_in[4];
  const float* Wb_     = (const float*)d_in[5];
  const float* Wg      = (const float*)d_in[6];
  const float* Wo      = (const float*)d_in[7];
  const float* conv_q  = (const float*)d_in[8];
  const float* conv_k  = (const float*)d_in[9];
  const float* conv_v  = (const float*)d_in[10];
  const float* A_log   = (const float*)d_in[11];
  const float* dt_bias = (const float*)d_in[12];
  const float* w_norm  = (const float*)d_in[13];
  float* out = (float*)d_out;

  // ---- workspace layout (float offsets) ----------------------------------
  // pre   [S][6144]              @ 0           25,165,824
  // qn    bf16 S*1024            @ 25,165,824   2,097,152   (ogb after phaseA)
  // kn    bf16 S*1024            @ 27,262,976   2,097,152
  // vcb   f32 S*2048 (obuf)      @ 29,360,128   8,388,608
  // a/b/gl/beta                  @ 37,748,736   4*65,536
  // lam                          @ 38,010,880   65,536
  // arena: xb|wts|wo             @ 38,076,416  12,582,912
  //   amNeg bf16 overlays xb+wts @ 38,076,416   8,388,608 (ends 46,465,024 < wo)
  // Bm    bf16                   @ 50,659,328   8,388,608
  // q2    bf16                   @ 59,047,936   4,194,304
  // high-water 63,242,240 floats = 253 MB
  float* W = (float*)d_ws;
  float* pre   = W;
  __hip_bfloat16* qn = (__hip_bfloat16*)(W + 25165824);
  __hip_bfloat16* kn = (__hip_bfloat16*)(W + 27262976);
  float* vcb   = W + 29360128;
  float* a_pre = W + 37748736;
  float* b_pre = a_pre + 65536;
  float* glb   = b_pre + 65536;
  float* beta  = glb + 65536;
  float* lam   = W + 38010880;
  __hip_bfloat16* xb  = (__hip_bfloat16*)(W + 38076416);
  __hip_bfloat16* wts = xb + 8388608;          // 12,582,912 bf16 (q|k|v|g)
  __hip_bfloat16* wo  = wts + 12582912;        // 4,194,304 bf16
  __hip_bfloat16* amNeg = (__hip_bfloat16*)(W + 38076416); // over xb+wts
  __hip_bfloat16* Bmo = (__hip_bfloat16*)(W + 50659328);
  __hip_bfloat16* q2b = (__hip_bfloat16*)(W + 59047936);
  __hip_bfloat16* ogb = (__hip_bfloat16*)(W + 25165824);   // over qn+kn
  float* obuf = vcb;

  // 1. casts
  cast_f2b<<<(S_LEN*HID)/1024, 256, 0, stream>>>(x, xb, S_LEN*HID);
  cast5<<<16777216/1024, 256, 0, stream>>>(Wq, Wk, Wv, Wg, Wo, wts);
  // 2. tiny projections
  gemm_bt2<<<dim3(2, S_LEN/64), 256, 0, stream>>>(x, Wa, Wb_, a_pre, b_pre, HID);
  // 3. fused q|k|v|gate projection GEMM
  gemm_bf16_bt<<<dim3(NPROJ/128, S_LEN/128), 256, 0, stream>>>(xb, wts, pre, S_LEN, NPROJ, HID);
  // 4. convs + gating scalars
  conv_qk_kernel<<<dim3(S_LEN, 16), 128, 0, stream>>>(pre, conv_q, conv_k, qn, kn);
  conv_v_kernel<<<(S_LEN*VAL_DIM)/256, 256, 0, stream>>>(pre, conv_v, vcb);
  gb_kernel<<<(S_LEN*NVH)/256, 256, 0, stream>>>(a_pre, b_pre, A_log, dt_bias, glb, beta);
  // 5. chunk-local precompute + serial affine scan
  phaseA_kernel<<<dim3(NVH, NCH), 256, 0, stream>>>(qn, kn, vcb, glb, beta, amNeg, Bmo, q2b, lam);
  phaseB_kernel<<<2*NVH, 512, 0, stream>>>(q2b, amNeg, Bmo, lam, obuf);
  // 6. gated RMSNorm + output projection
  norm_kernel<<<dim3(S_LEN, NVH), 128, 0, stream>>>(obuf, pre, w_norm, ogb);
  gemm_bf16_bt<<<dim3(HID/128, S_LEN/128), 256, 0, stream>>>(ogb, wo, out, S_LEN, HID, VAL_DIM);
}